// Round 1
// baseline (504.521 us; speedup 1.0000x reference)
//
#include <hip/hip_runtime.h>
#include <hip/hip_bf16.h>
#include <stdint.h>

#define N_NODES  50000
#define N_EDGES  800000
#define N_GRAPHS 512

typedef __attribute__((ext_vector_type(8))) short  short8;
typedef __attribute__((ext_vector_type(4))) float  floatx4;
typedef unsigned short u16;
typedef unsigned int   u32;

__device__ __forceinline__ u16 f2b(float f){
  u32 u = __float_as_uint(f);
  u = (u + 0x7FFFu + ((u >> 16) & 1u)) >> 16;   // RNE
  return (u16)u;
}
__device__ __forceinline__ u32 pack2(float a, float b){
  return (u32)f2b(a) | ((u32)f2b(b) << 16);
}
__device__ __forceinline__ float blo(u32 v){ return __uint_as_float(v << 16); }
__device__ __forceinline__ float bhi(u32 v){ return __uint_as_float(v & 0xFFFF0000u); }
__device__ __forceinline__ float b2f(u16 s){ return __uint_as_float(((u32)s) << 16); }

// ---- CSR build -------------------------------------------------------------
__global__ void k_hist(const int* __restrict__ dst, int* __restrict__ deg){
  int i = blockIdx.x*blockDim.x + threadIdx.x;
  if (i < N_EDGES) atomicAdd(&deg[dst[i]], 1);
}

__global__ void k_scan(const int* __restrict__ deg, int* __restrict__ rowptr,
                       float* __restrict__ dinv){
  __shared__ int sums[1024];
  int t = threadIdx.x;
  const int per = (N_NODES + 1023) / 1024;  // 49
  int base = t * per;
  int s = 0;
  for (int i = 0; i < per; i++){ int idx = base + i; if (idx < N_NODES) s += deg[idx]; }
  sums[t] = s;
  __syncthreads();
  for (int off = 1; off < 1024; off <<= 1){
    int v = 0;
    if (t >= off) v = sums[t - off];
    __syncthreads();
    sums[t] += v;
    __syncthreads();
  }
  int run = sums[t] - s;  // exclusive prefix
  for (int i = 0; i < per; i++){
    int idx = base + i;
    if (idx < N_NODES){
      int d = deg[idx];
      rowptr[idx] = run;
      run += d;
      dinv[idx] = 1.0f / (float)max(d, 1);
    }
  }
  if (t == 1023) rowptr[N_NODES] = N_EDGES;
}

__global__ void k_scatter(const int* __restrict__ src, const int* __restrict__ dst,
                          const int* __restrict__ rowptr, int* __restrict__ fill,
                          int* __restrict__ col){
  int i = blockIdx.x*blockDim.x + threadIdx.x;
  if (i < N_EDGES){
    int d = dst[i];
    int p = atomicAdd(&fill[d], 1);
    col[rowptr[d] + p] = src[i];
  }
}

// ---- prep: x -> bf16, weights -> bf16 transposed+swizzled ------------------
__global__ void k_cast(const float4* __restrict__ x, uint2* __restrict__ out){
  int i = blockIdx.x*blockDim.x + threadIdx.x;
  if (i < N_NODES*128/4){
    float4 v = x[i];
    out[i] = make_uint2(pack2(v.x, v.y), pack2(v.z, v.w));
  }
}

// wcat[l] is [256 rows(n)][128 (k)] bf16, 16B chunks XOR-swizzled: chunk c of row n
// stored at position c ^ (n & 15). Rows 0..127 = Wrel^T, rows 128..255 = Wroot^T.
__global__ void k_prepw(const float* __restrict__ Wrel1, const float* __restrict__ Wroot1,
                        const float* __restrict__ Wrel2, const float* __restrict__ Wroot2,
                        const float* __restrict__ Wrel3, const float* __restrict__ Wroot3,
                        u16* __restrict__ wcat){
  int id = blockIdx.x*blockDim.x + threadIdx.x;
  if (id >= 3*256*128) return;
  int l = id >> 15;
  int r = id & 32767;
  int n = r >> 7;
  int k = r & 127;
  const float* Wrel  = (l==0) ? Wrel1  : (l==1) ? Wrel2  : Wrel3;
  const float* Wroot = (l==0) ? Wroot1 : (l==1) ? Wroot2 : Wroot3;
  float w = (n < 128) ? Wrel[k*128 + n] : Wroot[k*128 + (n - 128)];
  int c = k >> 3, j = k & 7;
  wcat[l*32768 + n*128 + ((c ^ (n & 15)) << 3) + j] = f2b(w);
}

// ---- GEMM: [Y|Z] = A(bf16) @ [Wrel|Wroot]  (M=50000, K=128, N=256) ---------
// Block: 128 rows x 256 cols, 4 waves in 2x2; wave tile 64x128 (m=4,n=8 MFMA tiles).
// A fragments straight from global (each element read once); B from swizzled LDS.
__launch_bounds__(256, 2)
__global__ void k_gemm(const u16* __restrict__ A, const u16* __restrict__ Wcat,
                       u16* __restrict__ Y, float* __restrict__ Z){
  __shared__ u16 Bs[256*128];
  {
    const uint4* s = (const uint4*)Wcat;
    uint4* d = (uint4*)Bs;
    #pragma unroll
    for (int i = 0; i < 16; i++) d[threadIdx.x + 256*i] = s[threadIdx.x + 256*i];
  }
  __syncthreads();

  int wave = threadIdx.x >> 6, lane = threadIdx.x & 63;
  int l15 = lane & 15, quad = lane >> 4;
  int wy = wave >> 1, wx = wave & 1;
  int rowBase = blockIdx.x*128 + wy*64;

  floatx4 acc[4][8] = {};

  #pragma unroll
  for (int k0 = 0; k0 < 128; k0 += 32){
    int c = (k0 >> 3) + quad;
    short8 a[4];
    #pragma unroll
    for (int mt = 0; mt < 4; mt++){
      int row = rowBase + mt*16 + l15;
      if (row > N_NODES-1) row = N_NODES-1;   // clamp; stores are masked
      a[mt] = *(const short8*)(A + row*128 + k0 + quad*8);
    }
    #pragma unroll
    for (int nt = 0; nt < 8; nt++){
      int n = wx*128 + nt*16 + l15;
      short8 b = *(const short8*)(Bs + n*128 + ((c ^ (n & 15)) << 3));
      #pragma unroll
      for (int mt = 0; mt < 4; mt++)
        acc[mt][nt] = __builtin_amdgcn_mfma_f32_16x16x32_bf16(a[mt], b, acc[mt][nt], 0, 0, 0);
    }
  }

  #pragma unroll
  for (int mt = 0; mt < 4; mt++){
    int rbase = rowBase + mt*16 + quad*4;
    #pragma unroll
    for (int r = 0; r < 4; r++){
      int row = rbase + r;
      if (row < N_NODES){
        #pragma unroll
        for (int nt = 0; nt < 8; nt++){
          int coln = nt*16 + l15;
          float v = acc[mt][nt][r];
          if (wx == 0) Y[row*128 + coln] = f2b(v);
          else         Z[row*128 + coln] = v;
        }
      }
    }
  }
}

// ---- Aggregation: h = act(dinv * sum_{j in N(i)} Y[j] + brel + Z[i]) -------
// One wave per node, 2 channels per lane (packed bf16x2 reads of Y rows).
__global__ void k_agg(const u16* __restrict__ Y, const float* __restrict__ Z,
                      const int* __restrict__ rowptr, const int* __restrict__ col,
                      const float* __restrict__ dinv, const float* __restrict__ brel,
                      u16* __restrict__ Xout, int do_relu){
  int wave = threadIdx.x >> 6, lane = threadIdx.x & 63;
  int node = blockIdx.x*4 + wave;
  if (node >= N_NODES) return;
  int s = rowptr[node], e = rowptr[node+1];
  const u32* Yu = (const u32*)Y;
  float s0 = 0.f, s1 = 0.f;
  for (int cb = s; cb < e; cb += 64){
    int cnt = min(64, e - cb);
    int idx = 0;
    if (cb + lane < e) idx = col[cb + lane];
    int k = 0;
    for (; k + 4 <= cnt; k += 4){
      int j0 = __shfl(idx, k),   j1 = __shfl(idx, k+1);
      int j2 = __shfl(idx, k+2), j3 = __shfl(idx, k+3);
      u32 v0 = Yu[j0*64 + lane], v1 = Yu[j1*64 + lane];
      u32 v2 = Yu[j2*64 + lane], v3 = Yu[j3*64 + lane];
      s0 += (blo(v0) + blo(v1)) + (blo(v2) + blo(v3));
      s1 += (bhi(v0) + bhi(v1)) + (bhi(v2) + bhi(v3));
    }
    for (; k < cnt; k++){
      int j = __shfl(idx, k);
      u32 v = Yu[j*64 + lane];
      s0 += blo(v); s1 += bhi(v);
    }
  }
  float di = dinv[node];
  float2 z  = *(const float2*)(Z + node*128 + 2*lane);
  float2 bb = *(const float2*)(brel + 2*lane);
  float h0 = fmaf(s0, di, bb.x + z.x);
  float h1 = fmaf(s1, di, bb.y + z.y);
  if (do_relu){ h0 = fmaxf(h0, 0.f); h1 = fmaxf(h1, 0.f); }
  ((u32*)Xout)[node*64 + lane] = pack2(h0, h1);
}

// ---- graph boundaries (batch is sorted) ------------------------------------
__global__ void k_bounds(const int* __restrict__ batch, int* __restrict__ start){
  int g = threadIdx.x + blockIdx.x*blockDim.x;
  if (g > N_GRAPHS) return;
  int lo = 0, hi = N_NODES;
  while (lo < hi){ int mid = (lo + hi) >> 1; if (batch[mid] < g) lo = mid + 1; else hi = mid; }
  start[g] = lo;
}

// ---- mean pool + 3-layer MLP, fused; one block per graph -------------------
__launch_bounds__(128)
__global__ void k_pool_mlp(const u16* __restrict__ H3, const int* __restrict__ start,
                           const float* __restrict__ W1, const float* __restrict__ b1,
                           const float* __restrict__ W2, const float* __restrict__ b2,
                           const float* __restrict__ Wo, const float* __restrict__ bo,
                           float* __restrict__ out){
  __shared__ float g[128], h1[128], h2[128];
  int gid = blockIdx.x, t = threadIdx.x;
  int s = start[gid], e = start[gid+1];
  float sum = 0.f;
  for (int i = s; i < e; i++) sum += b2f(H3[i*128 + t]);
  g[t] = sum / (float)max(e - s, 1);
  __syncthreads();
  float a = b1[t];
  for (int k = 0; k < 128; k++) a = fmaf(g[k], W1[k*128 + t], a);
  h1[t] = fmaxf(a, 0.f);
  __syncthreads();
  float c = b2[t];
  for (int k = 0; k < 128; k++) c = fmaf(h1[k], W2[k*128 + t], c);
  h2[t] = fmaxf(c, 0.f);
  __syncthreads();
  if (t < 8){
    float o = bo[t];
    for (int k = 0; k < 128; k++) o = fmaf(h2[k], Wo[k*8 + t], o);
    out[gid*8 + t] = o;
  }
}

extern "C" void kernel_launch(void* const* d_in, const int* in_sizes, int n_in,
                              void* d_out, int out_size, void* d_ws, size_t ws_size,
                              hipStream_t stream){
  const float* x     = (const float*)d_in[0];
  const int*   ei    = (const int*)d_in[1];
  const int*   batch = (const int*)d_in[2];
  const float* Wrel[3]  = {(const float*)d_in[3], (const float*)d_in[6], (const float*)d_in[9]};
  const float* brel[3]  = {(const float*)d_in[4], (const float*)d_in[7], (const float*)d_in[10]};
  const float* Wroot[3] = {(const float*)d_in[5], (const float*)d_in[8], (const float*)d_in[11]};
  const float* W1 = (const float*)d_in[12]; const float* b1 = (const float*)d_in[13];
  const float* W2 = (const float*)d_in[14]; const float* b2 = (const float*)d_in[15];
  const float* Wo = (const float*)d_in[16]; const float* bo = (const float*)d_in[17];
  const int* esrc = ei;
  const int* edst = ei + N_EDGES;

  char* ws = (char*)d_ws;
  size_t off = 0;
  auto alloc = [&](size_t bytes)->char*{
    char* p = ws + off; off += (bytes + 255) & ~(size_t)255; return p;
  };
  u16*   Y      = (u16*)  alloc((size_t)N_NODES*128*2);
  float* Z      = (float*)alloc((size_t)N_NODES*128*4);
  u16*   XA     = (u16*)  alloc((size_t)N_NODES*128*2);
  u16*   XB     = (u16*)  alloc((size_t)N_NODES*128*2);
  u16*   wcat   = (u16*)  alloc((size_t)3*256*128*2);
  int*   deg    = (int*)  alloc((size_t)N_NODES*4);
  int*   fill   = (int*)  alloc((size_t)N_NODES*4);
  int*   rowptr = (int*)  alloc((size_t)(N_NODES+1)*4);
  float* dinv   = (float*)alloc((size_t)N_NODES*4);
  int*   colIdx = (int*)  alloc((size_t)N_EDGES*4);
  int*   start  = (int*)  alloc((size_t)(N_GRAPHS+1)*4);

  hipMemsetAsync(deg,  0, (size_t)N_NODES*4, stream);
  hipMemsetAsync(fill, 0, (size_t)N_NODES*4, stream);

  dim3 b256(256);
  k_hist   <<<(N_EDGES+255)/256, b256, 0, stream>>>(edst, deg);
  k_scan   <<<1, 1024, 0, stream>>>(deg, rowptr, dinv);
  k_scatter<<<(N_EDGES+255)/256, b256, 0, stream>>>(esrc, edst, rowptr, fill, colIdx);
  k_cast   <<<(N_NODES*128/4+255)/256, b256, 0, stream>>>((const float4*)x, (uint2*)XA);
  k_prepw  <<<(3*256*128+255)/256, b256, 0, stream>>>(Wrel[0],Wroot[0],Wrel[1],Wroot[1],
                                                      Wrel[2],Wroot[2], wcat);
  k_bounds <<<3, 256, 0, stream>>>(batch, start);

  const int ggrid = (N_NODES + 127)/128;   // 391
  const int agrid = (N_NODES + 3)/4;       // 12500

  k_gemm<<<ggrid, b256, 0, stream>>>(XA, wcat + 0*32768, Y, Z);
  k_agg <<<agrid, b256, 0, stream>>>(Y, Z, rowptr, colIdx, dinv, brel[0], XB, 1);

  k_gemm<<<ggrid, b256, 0, stream>>>(XB, wcat + 1*32768, Y, Z);
  k_agg <<<agrid, b256, 0, stream>>>(Y, Z, rowptr, colIdx, dinv, brel[1], XA, 1);

  k_gemm<<<ggrid, b256, 0, stream>>>(XA, wcat + 2*32768, Y, Z);
  k_agg <<<agrid, b256, 0, stream>>>(Y, Z, rowptr, colIdx, dinv, brel[2], XB, 0);

  k_pool_mlp<<<N_GRAPHS, 128, 0, stream>>>(XB, start, W1, b1, W2, b2, Wo, bo, (float*)d_out);
}

// Round 2
// 396.950 us; speedup vs baseline: 1.2710x; 1.2710x over previous
//
#include <hip/hip_runtime.h>
#include <hip/hip_bf16.h>
#include <stdint.h>

#define N_NODES  50000
#define N_EDGES  800000
#define N_GRAPHS 512

#define SB  512                      // elements per scan block
#define NSB ((N_NODES + SB - 1)/SB)  // 98

typedef __attribute__((ext_vector_type(8))) short  short8;
typedef __attribute__((ext_vector_type(4))) float  floatx4;
typedef unsigned short u16;
typedef unsigned int   u32;

__device__ __forceinline__ u16 f2b(float f){
  u32 u = __float_as_uint(f);
  u = (u + 0x7FFFu + ((u >> 16) & 1u)) >> 16;   // RNE
  return (u16)u;
}
__device__ __forceinline__ u32 pack2(float a, float b){
  return (u32)f2b(a) | ((u32)f2b(b) << 16);
}
__device__ __forceinline__ float blo(u32 v){ return __uint_as_float(v << 16); }
__device__ __forceinline__ float bhi(u32 v){ return __uint_as_float(v & 0xFFFF0000u); }
__device__ __forceinline__ float b2f(u16 s){ return __uint_as_float(((u32)s) << 16); }

// ---- CSR build -------------------------------------------------------------
__global__ void k_hist(const int* __restrict__ dst, int* __restrict__ deg){
  int i = blockIdx.x*blockDim.x + threadIdx.x;
  if (i < N_EDGES) atomicAdd(&deg[dst[i]], 1);
}

// block sums of deg (coalesced)
__global__ void k_psum(const int* __restrict__ deg, int* __restrict__ bsum){
  __shared__ int red[8];
  int t = threadIdx.x;
  int idx = blockIdx.x*SB + t;
  int v = (idx < N_NODES) ? deg[idx] : 0;
  int s = v;
  s += __shfl_down(s, 32); s += __shfl_down(s, 16); s += __shfl_down(s, 8);
  s += __shfl_down(s, 4);  s += __shfl_down(s, 2);  s += __shfl_down(s, 1);
  if ((t & 63) == 0) red[t >> 6] = s;
  __syncthreads();
  if (t == 0){
    int a = 0;
    #pragma unroll
    for (int i = 0; i < 8; i++) a += red[i];
    bsum[blockIdx.x] = a;
  }
}

// scan the 98 block sums (tiny, 1 block)
__global__ void k_sscan(const int* __restrict__ bsum, int* __restrict__ bpre,
                        int* __restrict__ rowptr){
  __shared__ int s[128];
  int t = threadIdx.x;
  int v = (t < NSB) ? bsum[t] : 0;
  s[t] = v;
  __syncthreads();
  for (int off = 1; off < 128; off <<= 1){
    int u = (t >= off) ? s[t - off] : 0;
    __syncthreads();
    s[t] += u;
    __syncthreads();
  }
  if (t < NSB) bpre[t] = s[t] - v;   // exclusive prefix of block sums
  if (t == 0) rowptr[N_NODES] = N_EDGES;
}

// in-block exclusive scan + add block prefix -> rowptr, dinv
__global__ void k_emit(const int* __restrict__ deg, const int* __restrict__ bpre,
                       int* __restrict__ rowptr, float* __restrict__ dinv){
  __shared__ int s[SB];
  int t = threadIdx.x;
  int idx = blockIdx.x*SB + t;
  int v = (idx < N_NODES) ? deg[idx] : 0;
  s[t] = v;
  __syncthreads();
  for (int off = 1; off < SB; off <<= 1){
    int u = (t >= off) ? s[t - off] : 0;
    __syncthreads();
    s[t] += u;
    __syncthreads();
  }
  if (idx < N_NODES){
    rowptr[idx] = bpre[blockIdx.x] + s[t] - v;
    dinv[idx] = 1.0f / (float)max(v, 1);
  }
}

__global__ void k_scatter(const int* __restrict__ src, const int* __restrict__ dst,
                          const int* __restrict__ rowptr, int* __restrict__ fill,
                          int* __restrict__ col){
  int i = blockIdx.x*blockDim.x + threadIdx.x;
  if (i < N_EDGES){
    int d = dst[i];
    int p = atomicAdd(&fill[d], 1);
    col[rowptr[d] + p] = src[i];
  }
}

// ---- prep: x -> bf16, weights -> bf16 transposed+swizzled ------------------
__global__ void k_cast(const float4* __restrict__ x, uint2* __restrict__ out){
  int i = blockIdx.x*blockDim.x + threadIdx.x;
  if (i < N_NODES*128/4){
    float4 v = x[i];
    out[i] = make_uint2(pack2(v.x, v.y), pack2(v.z, v.w));
  }
}

// wcat[l] is [256 rows(n)][128 (k)] bf16, 16B chunks XOR-swizzled: chunk c of row n
// stored at position c ^ (n & 15). Rows 0..127 = Wrel^T, rows 128..255 = Wroot^T.
__global__ void k_prepw(const float* __restrict__ Wrel1, const float* __restrict__ Wroot1,
                        const float* __restrict__ Wrel2, const float* __restrict__ Wroot2,
                        const float* __restrict__ Wrel3, const float* __restrict__ Wroot3,
                        u16* __restrict__ wcat){
  int id = blockIdx.x*blockDim.x + threadIdx.x;
  if (id >= 3*256*128) return;
  int l = id >> 15;
  int r = id & 32767;
  int n = r >> 7;
  int k = r & 127;
  const float* Wrel  = (l==0) ? Wrel1  : (l==1) ? Wrel2  : Wrel3;
  const float* Wroot = (l==0) ? Wroot1 : (l==1) ? Wroot2 : Wroot3;
  float w = (n < 128) ? Wrel[k*128 + n] : Wroot[k*128 + (n - 128)];
  int c = k >> 3, j = k & 7;
  wcat[l*32768 + n*128 + ((c ^ (n & 15)) << 3) + j] = f2b(w);
}

// ---- GEMM: [Y|Z] = A(bf16) @ [Wrel|Wroot]  (M=50000, K=128, N=256) ---------
__launch_bounds__(256, 2)
__global__ void k_gemm(const u16* __restrict__ A, const u16* __restrict__ Wcat,
                       u16* __restrict__ Y, float* __restrict__ Z){
  __shared__ u16 Bs[256*128];
  {
    const uint4* s = (const uint4*)Wcat;
    uint4* d = (uint4*)Bs;
    #pragma unroll
    for (int i = 0; i < 16; i++) d[threadIdx.x + 256*i] = s[threadIdx.x + 256*i];
  }
  __syncthreads();

  int wave = threadIdx.x >> 6, lane = threadIdx.x & 63;
  int l15 = lane & 15, quad = lane >> 4;
  int wy = wave >> 1, wx = wave & 1;
  int rowBase = blockIdx.x*128 + wy*64;

  floatx4 acc[4][8] = {};

  #pragma unroll
  for (int k0 = 0; k0 < 128; k0 += 32){
    int c = (k0 >> 3) + quad;
    short8 a[4];
    #pragma unroll
    for (int mt = 0; mt < 4; mt++){
      int row = rowBase + mt*16 + l15;
      if (row > N_NODES-1) row = N_NODES-1;   // clamp; stores are masked
      a[mt] = *(const short8*)(A + row*128 + k0 + quad*8);
    }
    #pragma unroll
    for (int nt = 0; nt < 8; nt++){
      int n = wx*128 + nt*16 + l15;
      short8 b = *(const short8*)(Bs + n*128 + ((c ^ (n & 15)) << 3));
      #pragma unroll
      for (int mt = 0; mt < 4; mt++)
        acc[mt][nt] = __builtin_amdgcn_mfma_f32_16x16x32_bf16(a[mt], b, acc[mt][nt], 0, 0, 0);
    }
  }

  #pragma unroll
  for (int mt = 0; mt < 4; mt++){
    int rbase = rowBase + mt*16 + quad*4;
    #pragma unroll
    for (int r = 0; r < 4; r++){
      int row = rbase + r;
      if (row < N_NODES){
        #pragma unroll
        for (int nt = 0; nt < 8; nt++){
          int coln = nt*16 + l15;
          float v = acc[mt][nt][r];
          if (wx == 0) Y[row*128 + coln] = f2b(v);
          else         Z[row*128 + coln] = v;
        }
      }
    }
  }
}

// ---- Aggregation: h = act(dinv * sum_{j in N(i)} Y[j] + brel + Z[i]) -------
__global__ void k_agg(const u16* __restrict__ Y, const float* __restrict__ Z,
                      const int* __restrict__ rowptr, const int* __restrict__ col,
                      const float* __restrict__ dinv, const float* __restrict__ brel,
                      u16* __restrict__ Xout, int do_relu){
  int wave = threadIdx.x >> 6, lane = threadIdx.x & 63;
  int node = blockIdx.x*4 + wave;
  if (node >= N_NODES) return;
  int s = rowptr[node], e = rowptr[node+1];
  const u32* Yu = (const u32*)Y;
  float s0 = 0.f, s1 = 0.f;
  for (int cb = s; cb < e; cb += 64){
    int cnt = min(64, e - cb);
    int idx = 0;
    if (cb + lane < e) idx = col[cb + lane];
    int k = 0;
    for (; k + 4 <= cnt; k += 4){
      int j0 = __shfl(idx, k),   j1 = __shfl(idx, k+1);
      int j2 = __shfl(idx, k+2), j3 = __shfl(idx, k+3);
      u32 v0 = Yu[j0*64 + lane], v1 = Yu[j1*64 + lane];
      u32 v2 = Yu[j2*64 + lane], v3 = Yu[j3*64 + lane];
      s0 += (blo(v0) + blo(v1)) + (blo(v2) + blo(v3));
      s1 += (bhi(v0) + bhi(v1)) + (bhi(v2) + bhi(v3));
    }
    for (; k < cnt; k++){
      int j = __shfl(idx, k);
      u32 v = Yu[j*64 + lane];
      s0 += blo(v); s1 += bhi(v);
    }
  }
  float di = dinv[node];
  float2 z  = *(const float2*)(Z + node*128 + 2*lane);
  float2 bb = *(const float2*)(brel + 2*lane);
  float h0 = fmaf(s0, di, bb.x + z.x);
  float h1 = fmaf(s1, di, bb.y + z.y);
  if (do_relu){ h0 = fmaxf(h0, 0.f); h1 = fmaxf(h1, 0.f); }
  ((u32*)Xout)[node*64 + lane] = pack2(h0, h1);
}

// ---- graph boundaries (batch is sorted) ------------------------------------
__global__ void k_bounds(const int* __restrict__ batch, int* __restrict__ start){
  int g = threadIdx.x + blockIdx.x*blockDim.x;
  if (g > N_GRAPHS) return;
  int lo = 0, hi = N_NODES;
  while (lo < hi){ int mid = (lo + hi) >> 1; if (batch[mid] < g) lo = mid + 1; else hi = mid; }
  start[g] = lo;
}

// ---- mean pool + 3-layer MLP, fused; one block per graph -------------------
__launch_bounds__(128)
__global__ void k_pool_mlp(const u16* __restrict__ H3, const int* __restrict__ start,
                           const float* __restrict__ W1, const float* __restrict__ b1,
                           const float* __restrict__ W2, const float* __restrict__ b2,
                           const float* __restrict__ Wo, const float* __restrict__ bo,
                           float* __restrict__ out){
  __shared__ float g[128], h1[128], h2[128];
  int gid = blockIdx.x, t = threadIdx.x;
  int s = start[gid], e = start[gid+1];
  float sum = 0.f;
  for (int i = s; i < e; i++) sum += b2f(H3[i*128 + t]);
  g[t] = sum / (float)max(e - s, 1);
  __syncthreads();
  float a = b1[t];
  for (int k = 0; k < 128; k++) a = fmaf(g[k], W1[k*128 + t], a);
  h1[t] = fmaxf(a, 0.f);
  __syncthreads();
  float c = b2[t];
  for (int k = 0; k < 128; k++) c = fmaf(h1[k], W2[k*128 + t], c);
  h2[t] = fmaxf(c, 0.f);
  __syncthreads();
  if (t < 8){
    float o = bo[t];
    for (int k = 0; k < 128; k++) o = fmaf(h2[k], Wo[k*8 + t], o);
    out[gid*8 + t] = o;
  }
}

extern "C" void kernel_launch(void* const* d_in, const int* in_sizes, int n_in,
                              void* d_out, int out_size, void* d_ws, size_t ws_size,
                              hipStream_t stream){
  const float* x     = (const float*)d_in[0];
  const int*   ei    = (const int*)d_in[1];
  const int*   batch = (const int*)d_in[2];
  const float* Wrel[3]  = {(const float*)d_in[3], (const float*)d_in[6], (const float*)d_in[9]};
  const float* brel[3]  = {(const float*)d_in[4], (const float*)d_in[7], (const float*)d_in[10]};
  const float* Wroot[3] = {(const float*)d_in[5], (const float*)d_in[8], (const float*)d_in[11]};
  const float* W1 = (const float*)d_in[12]; const float* b1 = (const float*)d_in[13];
  const float* W2 = (const float*)d_in[14]; const float* b2 = (const float*)d_in[15];
  const float* Wo = (const float*)d_in[16]; const float* bo = (const float*)d_in[17];
  const int* esrc = ei;
  const int* edst = ei + N_EDGES;

  char* ws = (char*)d_ws;
  size_t off = 0;
  auto alloc = [&](size_t bytes)->char*{
    char* p = ws + off; off += (bytes + 255) & ~(size_t)255; return p;
  };
  u16*   Y      = (u16*)  alloc((size_t)N_NODES*128*2);
  float* Z      = (float*)alloc((size_t)N_NODES*128*4);
  u16*   XA     = (u16*)  alloc((size_t)N_NODES*128*2);
  u16*   XB     = (u16*)  alloc((size_t)N_NODES*128*2);
  u16*   wcat   = (u16*)  alloc((size_t)3*256*128*2);
  int*   deg    = (int*)  alloc((size_t)N_NODES*4);
  int*   fill   = (int*)  alloc((size_t)N_NODES*4);
  int*   rowptr = (int*)  alloc((size_t)(N_NODES+1)*4);
  float* dinv   = (float*)alloc((size_t)N_NODES*4);
  int*   colIdx = (int*)  alloc((size_t)N_EDGES*4);
  int*   start  = (int*)  alloc((size_t)(N_GRAPHS+1)*4);
  int*   bsum   = (int*)  alloc((size_t)NSB*4);
  int*   bpre   = (int*)  alloc((size_t)NSB*4);

  hipMemsetAsync(deg,  0, (size_t)N_NODES*4, stream);
  hipMemsetAsync(fill, 0, (size_t)N_NODES*4, stream);

  dim3 b256(256);
  k_hist   <<<(N_EDGES+255)/256, b256, 0, stream>>>(edst, deg);
  k_psum   <<<NSB, SB, 0, stream>>>(deg, bsum);
  k_sscan  <<<1, 128, 0, stream>>>(bsum, bpre, rowptr);
  k_emit   <<<NSB, SB, 0, stream>>>(deg, bpre, rowptr, dinv);
  k_scatter<<<(N_EDGES+255)/256, b256, 0, stream>>>(esrc, edst, rowptr, fill, colIdx);
  k_cast   <<<(N_NODES*128/4+255)/256, b256, 0, stream>>>((const float4*)x, (uint2*)XA);
  k_prepw  <<<(3*256*128+255)/256, b256, 0, stream>>>(Wrel[0],Wroot[0],Wrel[1],Wroot[1],
                                                      Wrel[2],Wroot[2], wcat);
  k_bounds <<<3, 256, 0, stream>>>(batch, start);

  const int ggrid = (N_NODES + 127)/128;   // 391
  const int agrid = (N_NODES + 3)/4;       // 12500

  k_gemm<<<ggrid, b256, 0, stream>>>(XA, wcat + 0*32768, Y, Z);
  k_agg <<<agrid, b256, 0, stream>>>(Y, Z, rowptr, colIdx, dinv, brel[0], XB, 1);

  k_gemm<<<ggrid, b256, 0, stream>>>(XB, wcat + 1*32768, Y, Z);
  k_agg <<<agrid, b256, 0, stream>>>(Y, Z, rowptr, colIdx, dinv, brel[1], XA, 1);

  k_gemm<<<ggrid, b256, 0, stream>>>(XA, wcat + 2*32768, Y, Z);
  k_agg <<<agrid, b256, 0, stream>>>(Y, Z, rowptr, colIdx, dinv, brel[2], XB, 0);

  k_pool_mlp<<<N_GRAPHS, 128, 0, stream>>>(XB, start, W1, b1, W2, b2, Wo, bo, (float*)d_out);
}

// Round 3
// 340.854 us; speedup vs baseline: 1.4802x; 1.1646x over previous
//
#include <hip/hip_runtime.h>
#include <hip/hip_bf16.h>
#include <stdint.h>

#define N_NODES  50000
#define N_EDGES  800000
#define N_GRAPHS 512

#define BINSZ   128
#define NBIN    ((N_NODES + BINSZ - 1)/BINSZ)    // 391
#define NCHUNK  256
#define CHUNK   ((N_EDGES + NCHUNK - 1)/NCHUNK)  // 3125
#define MAXBIN  3072                             // >> mean 2048 + 22 sigma

typedef __attribute__((ext_vector_type(8))) short  short8;
typedef __attribute__((ext_vector_type(4))) float  floatx4;
typedef unsigned short u16;
typedef unsigned int   u32;

__device__ __forceinline__ u16 f2b(float f){
  u32 u = __float_as_uint(f);
  u = (u + 0x7FFFu + ((u >> 16) & 1u)) >> 16;   // RNE
  return (u16)u;
}
__device__ __forceinline__ u32 pack2(float a, float b){
  return (u32)f2b(a) | ((u32)f2b(b) << 16);
}
__device__ __forceinline__ float blo(u32 v){ return __uint_as_float(v << 16); }
__device__ __forceinline__ float bhi(u32 v){ return __uint_as_float(v & 0xFFFF0000u); }
__device__ __forceinline__ float b2f(u16 s){ return __uint_as_float(((u32)s) << 16); }

// ---- CSR build via 2-level binning (all global writes coalesced-ish) -------
// 1) per-chunk histogram over 391 bins
__global__ void k_binhist(const int* __restrict__ dst, int* __restrict__ cnt,
                          int* __restrict__ bintotal){
  __shared__ int h[NBIN];
  int t = threadIdx.x;
  for (int i = t; i < NBIN; i += 256) h[i] = 0;
  __syncthreads();
  int base = blockIdx.x*CHUNK;
  int end  = min(base + CHUNK, N_EDGES);
  for (int i = base + t; i < end; i += 256) atomicAdd(&h[dst[i] >> 7], 1);
  __syncthreads();
  for (int i = t; i < NBIN; i += 256){
    cnt[blockIdx.x*NBIN + i] = h[i];           // coalesced
    if (h[i]) atomicAdd(&bintotal[i], h[i]);
  }
}

// 2) scan bin totals -> binstart
__global__ void k_binstart(const int* __restrict__ bintotal, int* __restrict__ binstart,
                           int* __restrict__ rowptr){
  __shared__ int s[512];
  int t = threadIdx.x;
  int v = (t < NBIN) ? bintotal[t] : 0;
  s[t] = v;
  __syncthreads();
  for (int off = 1; off < 512; off <<= 1){
    int u = (t >= off) ? s[t - off] : 0;
    __syncthreads();
    s[t] += u;
    __syncthreads();
  }
  if (t < NBIN) binstart[t] = s[t] - v;
  if (t == 0){ binstart[NBIN] = N_EDGES; rowptr[N_NODES] = N_EDGES; }
}

// 3) per-(chunk,bin) write offsets: block b scans cnt[c][b] over chunks
__global__ void k_chunkoff(const int* __restrict__ cnt, const int* __restrict__ binstart,
                           int* __restrict__ chunkoff){
  __shared__ int s[NCHUNK];
  int b = blockIdx.x, c = threadIdx.x;
  int v = cnt[c*NBIN + b];
  s[c] = v;
  __syncthreads();
  for (int off = 1; off < NCHUNK; off <<= 1){
    int u = (c >= off) ? s[c - off] : 0;
    __syncthreads();
    s[c] += u;
    __syncthreads();
  }
  chunkoff[c*NBIN + b] = binstart[b] + s[c] - v;
}

// 4) scatter packed records (dstlocal<<16 | src) into bin segments
__global__ void k_binscatter(const int* __restrict__ src, const int* __restrict__ dst,
                             const int* __restrict__ chunkoff, u32* __restrict__ rec){
  __shared__ int cur[NBIN];
  int t = threadIdx.x;
  for (int i = t; i < NBIN; i += 256) cur[i] = chunkoff[blockIdx.x*NBIN + i];
  __syncthreads();
  int base = blockIdx.x*CHUNK;
  int end  = min(base + CHUNK, N_EDGES);
  for (int i = base + t; i < end; i += 256){
    int d = dst[i], sv = src[i];
    int b = d >> 7;
    int p = atomicAdd(&cur[b], 1);
    rec[p] = (u32)(((d & 127) << 16) | sv);
  }
}

// 5) per-bin: build node-ordered CSR segment in LDS, write out coalesced.
//    col may alias rec: segment fully staged in LDS before overwrite.
__global__ void k_bincsr(const u32* __restrict__ rec, const int* __restrict__ binstart,
                         int* __restrict__ rowptr, float* __restrict__ dinv,
                         int* __restrict__ col){
  __shared__ u32 recs[MAXBIN];
  __shared__ int colL[MAXBIN];
  __shared__ int deg[BINSZ];
  __shared__ int cursor[BINSZ];
  __shared__ int sc[BINSZ];
  int b = blockIdx.x, t = threadIdx.x;
  int s0 = binstart[b], e0 = binstart[b+1];
  int n = e0 - s0;
  if (t < BINSZ) deg[t] = 0;
  for (int i = t; i < n; i += 256) recs[i] = rec[s0 + i];
  __syncthreads();
  for (int i = t; i < n; i += 256) atomicAdd(&deg[(recs[i] >> 16) & 127], 1);
  __syncthreads();
  if (t < BINSZ) sc[t] = deg[t];
  __syncthreads();
  for (int off = 1; off < BINSZ; off <<= 1){
    int u = 0;
    if (t < BINSZ && t >= off) u = sc[t - off];
    __syncthreads();
    if (t < BINSZ) sc[t] += u;
    __syncthreads();
  }
  if (t < BINSZ){
    int pref = sc[t] - deg[t];
    cursor[t] = pref;
    int node = b*BINSZ + t;
    if (node < N_NODES){
      rowptr[node] = s0 + pref;
      dinv[node] = 1.0f / (float)max(deg[t], 1);
    }
  }
  __syncthreads();
  for (int i = t; i < n; i += 256){
    u32 r = recs[i];
    int p = atomicAdd(&cursor[(r >> 16) & 127], 1);
    colL[p] = (int)(r & 0xFFFFu);
  }
  __syncthreads();
  for (int i = t; i < n; i += 256) col[s0 + i] = colL[i];
}

// ---- prep: x -> bf16, weights -> bf16 transposed+swizzled ------------------
__global__ void k_cast(const float4* __restrict__ x, uint2* __restrict__ out){
  int i = blockIdx.x*blockDim.x + threadIdx.x;
  if (i < N_NODES*128/4){
    float4 v = x[i];
    out[i] = make_uint2(pack2(v.x, v.y), pack2(v.z, v.w));
  }
}

// wcat[l]: [256 rows(n)][128 (k)] bf16, 16B chunks XOR-swizzled (c ^= n&15).
// Rows 0..127 = Wrel^T, rows 128..255 = Wroot^T.
__global__ void k_prepw(const float* __restrict__ Wrel1, const float* __restrict__ Wroot1,
                        const float* __restrict__ Wrel2, const float* __restrict__ Wroot2,
                        const float* __restrict__ Wrel3, const float* __restrict__ Wroot3,
                        u16* __restrict__ wcat){
  int id = blockIdx.x*blockDim.x + threadIdx.x;
  if (id >= 3*256*128) return;
  int l = id >> 15;
  int r = id & 32767;
  int n = r >> 7;
  int k = r & 127;
  const float* Wrel  = (l==0) ? Wrel1  : (l==1) ? Wrel2  : Wrel3;
  const float* Wroot = (l==0) ? Wroot1 : (l==1) ? Wroot2 : Wroot3;
  float w = (n < 128) ? Wrel[k*128 + n] : Wroot[k*128 + (n - 128)];
  int c = k >> 3, j = k & 7;
  wcat[l*32768 + n*128 + ((c ^ (n & 15)) << 3) + j] = f2b(w);
}

// ---- GEMM: [Y|Z] = A(bf16) @ [Wrel|Wroot]  (M=50000, K=128, N=256) ---------
__launch_bounds__(256, 2)
__global__ void k_gemm(const u16* __restrict__ A, const u16* __restrict__ Wcat,
                       u16* __restrict__ Y, float* __restrict__ Z){
  __shared__ u16 Bs[256*128];
  {
    const uint4* s = (const uint4*)Wcat;
    uint4* d = (uint4*)Bs;
    #pragma unroll
    for (int i = 0; i < 16; i++) d[threadIdx.x + 256*i] = s[threadIdx.x + 256*i];
  }
  __syncthreads();

  int wave = threadIdx.x >> 6, lane = threadIdx.x & 63;
  int l15 = lane & 15, quad = lane >> 4;
  int wy = wave >> 1, wx = wave & 1;
  int rowBase = blockIdx.x*128 + wy*64;

  floatx4 acc[4][8] = {};

  #pragma unroll
  for (int k0 = 0; k0 < 128; k0 += 32){
    int c = (k0 >> 3) + quad;
    short8 a[4];
    #pragma unroll
    for (int mt = 0; mt < 4; mt++){
      int row = rowBase + mt*16 + l15;
      if (row > N_NODES-1) row = N_NODES-1;   // clamp; stores are masked
      a[mt] = *(const short8*)(A + row*128 + k0 + quad*8);
    }
    #pragma unroll
    for (int nt = 0; nt < 8; nt++){
      int n = wx*128 + nt*16 + l15;
      short8 b = *(const short8*)(Bs + n*128 + ((c ^ (n & 15)) << 3));
      #pragma unroll
      for (int mt = 0; mt < 4; mt++)
        acc[mt][nt] = __builtin_amdgcn_mfma_f32_16x16x32_bf16(a[mt], b, acc[mt][nt], 0, 0, 0);
    }
  }

  #pragma unroll
  for (int mt = 0; mt < 4; mt++){
    int rbase = rowBase + mt*16 + quad*4;
    #pragma unroll
    for (int r = 0; r < 4; r++){
      int row = rbase + r;
      if (row < N_NODES){
        #pragma unroll
        for (int nt = 0; nt < 8; nt++){
          int coln = nt*16 + l15;
          float v = acc[mt][nt][r];
          if (wx == 0) Y[row*128 + coln] = f2b(v);
          else         Z[row*128 + coln] = v;
        }
      }
    }
  }
}

// ---- Aggregation: h = act(dinv * sum_{j in N(i)} Y[j] + brel + Z[i]) -------
__global__ void k_agg(const u16* __restrict__ Y, const float* __restrict__ Z,
                      const int* __restrict__ rowptr, const int* __restrict__ col,
                      const float* __restrict__ dinv, const float* __restrict__ brel,
                      u16* __restrict__ Xout, int do_relu){
  int wave = threadIdx.x >> 6, lane = threadIdx.x & 63;
  int node = blockIdx.x*4 + wave;
  if (node >= N_NODES) return;
  int s = rowptr[node], e = rowptr[node+1];
  const u32* Yu = (const u32*)Y;
  float s0 = 0.f, s1 = 0.f;
  for (int cb = s; cb < e; cb += 64){
    int cnt = min(64, e - cb);
    int idx = 0;
    if (cb + lane < e) idx = col[cb + lane];
    int k = 0;
    for (; k + 4 <= cnt; k += 4){
      int j0 = __shfl(idx, k),   j1 = __shfl(idx, k+1);
      int j2 = __shfl(idx, k+2), j3 = __shfl(idx, k+3);
      u32 v0 = Yu[j0*64 + lane], v1 = Yu[j1*64 + lane];
      u32 v2 = Yu[j2*64 + lane], v3 = Yu[j3*64 + lane];
      s0 += (blo(v0) + blo(v1)) + (blo(v2) + blo(v3));
      s1 += (bhi(v0) + bhi(v1)) + (bhi(v2) + bhi(v3));
    }
    for (; k < cnt; k++){
      int j = __shfl(idx, k);
      u32 v = Yu[j*64 + lane];
      s0 += blo(v); s1 += bhi(v);
    }
  }
  float di = dinv[node];
  float2 z  = *(const float2*)(Z + node*128 + 2*lane);
  float2 bb = *(const float2*)(brel + 2*lane);
  float h0 = fmaf(s0, di, bb.x + z.x);
  float h1 = fmaf(s1, di, bb.y + z.y);
  if (do_relu){ h0 = fmaxf(h0, 0.f); h1 = fmaxf(h1, 0.f); }
  ((u32*)Xout)[node*64 + lane] = pack2(h0, h1);
}

// ---- graph boundaries (batch is sorted) ------------------------------------
__global__ void k_bounds(const int* __restrict__ batch, int* __restrict__ start){
  int g = threadIdx.x + blockIdx.x*blockDim.x;
  if (g > N_GRAPHS) return;
  int lo = 0, hi = N_NODES;
  while (lo < hi){ int mid = (lo + hi) >> 1; if (batch[mid] < g) lo = mid + 1; else hi = mid; }
  start[g] = lo;
}

// ---- mean pool + 3-layer MLP, fused; one block per graph -------------------
__launch_bounds__(128)
__global__ void k_pool_mlp(const u16* __restrict__ H3, const int* __restrict__ start,
                           const float* __restrict__ W1, const float* __restrict__ b1,
                           const float* __restrict__ W2, const float* __restrict__ b2,
                           const float* __restrict__ Wo, const float* __restrict__ bo,
                           float* __restrict__ out){
  __shared__ float g[128], h1[128], h2[128];
  int gid = blockIdx.x, t = threadIdx.x;
  int s = start[gid], e = start[gid+1];
  float sum = 0.f;
  for (int i = s; i < e; i++) sum += b2f(H3[i*128 + t]);
  g[t] = sum / (float)max(e - s, 1);
  __syncthreads();
  float a = b1[t];
  for (int k = 0; k < 128; k++) a = fmaf(g[k], W1[k*128 + t], a);
  h1[t] = fmaxf(a, 0.f);
  __syncthreads();
  float c = b2[t];
  for (int k = 0; k < 128; k++) c = fmaf(h1[k], W2[k*128 + t], c);
  h2[t] = fmaxf(c, 0.f);
  __syncthreads();
  if (t < 8){
    float o = bo[t];
    for (int k = 0; k < 128; k++) o = fmaf(h2[k], Wo[k*8 + t], o);
    out[gid*8 + t] = o;
  }
}

extern "C" void kernel_launch(void* const* d_in, const int* in_sizes, int n_in,
                              void* d_out, int out_size, void* d_ws, size_t ws_size,
                              hipStream_t stream){
  const float* x     = (const float*)d_in[0];
  const int*   ei    = (const int*)d_in[1];
  const int*   batch = (const int*)d_in[2];
  const float* Wrel[3]  = {(const float*)d_in[3], (const float*)d_in[6], (const float*)d_in[9]};
  const float* brel[3]  = {(const float*)d_in[4], (const float*)d_in[7], (const float*)d_in[10]};
  const float* Wroot[3] = {(const float*)d_in[5], (const float*)d_in[8], (const float*)d_in[11]};
  const float* W1 = (const float*)d_in[12]; const float* b1 = (const float*)d_in[13];
  const float* W2 = (const float*)d_in[14]; const float* b2 = (const float*)d_in[15];
  const float* Wo = (const float*)d_in[16]; const float* bo = (const float*)d_in[17];
  const int* esrc = ei;
  const int* edst = ei + N_EDGES;

  char* ws = (char*)d_ws;
  size_t off = 0;
  auto alloc = [&](size_t bytes)->char*{
    char* p = ws + off; off += (bytes + 255) & ~(size_t)255; return p;
  };
  u16*   Y      = (u16*)  alloc((size_t)N_NODES*128*2);
  float* Z      = (float*)alloc((size_t)N_NODES*128*4);
  u16*   XA     = (u16*)  alloc((size_t)N_NODES*128*2);
  u16*   XB     = (u16*)  alloc((size_t)N_NODES*128*2);
  u16*   wcat   = (u16*)  alloc((size_t)3*256*128*2);
  int*   rowptr = (int*)  alloc((size_t)(N_NODES+1)*4);
  float* dinv   = (float*)alloc((size_t)N_NODES*4);
  int*   colIdx = (int*)  alloc((size_t)N_EDGES*4);   // doubles as rec buffer
  int*   start  = (int*)  alloc((size_t)(N_GRAPHS+1)*4);
  int*   cnt    = (int*)  alloc((size_t)NCHUNK*NBIN*4);
  int*   coff   = (int*)  alloc((size_t)NCHUNK*NBIN*4);
  int*   btot   = (int*)  alloc((size_t)NBIN*4);
  int*   bstart = (int*)  alloc((size_t)(NBIN+1)*4);
  u32*   rec    = (u32*)colIdx;

  hipMemsetAsync(btot, 0, (size_t)NBIN*4, stream);

  dim3 b256(256);
  k_binhist   <<<NCHUNK, b256, 0, stream>>>(edst, cnt, btot);
  k_binstart  <<<1, 512, 0, stream>>>(btot, bstart, rowptr);
  k_chunkoff  <<<NBIN, NCHUNK, 0, stream>>>(cnt, bstart, coff);
  k_binscatter<<<NCHUNK, b256, 0, stream>>>(esrc, edst, coff, rec);
  k_bincsr    <<<NBIN, b256, 0, stream>>>(rec, bstart, rowptr, dinv, colIdx);
  k_cast      <<<(N_NODES*128/4+255)/256, b256, 0, stream>>>((const float4*)x, (uint2*)XA);
  k_prepw     <<<(3*256*128+255)/256, b256, 0, stream>>>(Wrel[0],Wroot[0],Wrel[1],Wroot[1],
                                                         Wrel[2],Wroot[2], wcat);
  k_bounds    <<<3, 256, 0, stream>>>(batch, start);

  const int ggrid = (N_NODES + 127)/128;   // 391
  const int agrid = (N_NODES + 3)/4;       // 12500

  k_gemm<<<ggrid, b256, 0, stream>>>(XA, wcat + 0*32768, Y, Z);
  k_agg <<<agrid, b256, 0, stream>>>(Y, Z, rowptr, colIdx, dinv, brel[0], XB, 1);

  k_gemm<<<ggrid, b256, 0, stream>>>(XB, wcat + 1*32768, Y, Z);
  k_agg <<<agrid, b256, 0, stream>>>(Y, Z, rowptr, colIdx, dinv, brel[1], XA, 1);

  k_gemm<<<ggrid, b256, 0, stream>>>(XA, wcat + 2*32768, Y, Z);
  k_agg <<<agrid, b256, 0, stream>>>(Y, Z, rowptr, colIdx, dinv, brel[2], XB, 0);

  k_pool_mlp<<<N_GRAPHS, 128, 0, stream>>>(XB, start, W1, b1, W2, b2, Wo, bo, (float*)d_out);
}

// Round 4
// 333.132 us; speedup vs baseline: 1.5145x; 1.0232x over previous
//
#include <hip/hip_runtime.h>
#include <hip/hip_bf16.h>
#include <stdint.h>

#define N_NODES  50000
#define N_EDGES  800000
#define N_GRAPHS 512

#define BINSZ   128
#define NBIN    ((N_NODES + BINSZ - 1)/BINSZ)    // 391
#define NCHUNK  256
#define CHUNK   ((N_EDGES + NCHUNK - 1)/NCHUNK)  // 3125
#define MAXBIN  3072

typedef __attribute__((ext_vector_type(8))) short  short8;
typedef __attribute__((ext_vector_type(4))) float  floatx4;
typedef unsigned short u16;
typedef unsigned int   u32;

__device__ __forceinline__ u16 f2b(float f){
  u32 u = __float_as_uint(f);
  u = (u + 0x7FFFu + ((u >> 16) & 1u)) >> 16;   // RNE
  return (u16)u;
}
__device__ __forceinline__ u32 pack2(float a, float b){
  return (u32)f2b(a) | ((u32)f2b(b) << 16);
}
__device__ __forceinline__ float blo(u32 v){ return __uint_as_float(v << 16); }
__device__ __forceinline__ float bhi(u32 v){ return __uint_as_float(v & 0xFFFF0000u); }
__device__ __forceinline__ float b2f(u16 s){ return __uint_as_float(((u32)s) << 16); }

// ---- CSR build via 2-level binning -----------------------------------------
__global__ void k_binhist(const int* __restrict__ dst, int* __restrict__ cnt,
                          int* __restrict__ bintotal){
  __shared__ int h[NBIN];
  int t = threadIdx.x;
  for (int i = t; i < NBIN; i += 256) h[i] = 0;
  __syncthreads();
  int base = blockIdx.x*CHUNK;
  int end  = min(base + CHUNK, N_EDGES);
  for (int i = base + t; i < end; i += 256) atomicAdd(&h[dst[i] >> 7], 1);
  __syncthreads();
  for (int i = t; i < NBIN; i += 256){
    cnt[blockIdx.x*NBIN + i] = h[i];
    if (h[i]) atomicAdd(&bintotal[i], h[i]);
  }
}

__global__ void k_binstart(const int* __restrict__ bintotal, int* __restrict__ binstart,
                           int* __restrict__ rowptr){
  __shared__ int s[512];
  int t = threadIdx.x;
  int v = (t < NBIN) ? bintotal[t] : 0;
  s[t] = v;
  __syncthreads();
  for (int off = 1; off < 512; off <<= 1){
    int u = (t >= off) ? s[t - off] : 0;
    __syncthreads();
    s[t] += u;
    __syncthreads();
  }
  if (t < NBIN) binstart[t] = s[t] - v;
  if (t == 0){ binstart[NBIN] = N_EDGES; rowptr[N_NODES] = N_EDGES; }
}

__global__ void k_chunkoff(const int* __restrict__ cnt, const int* __restrict__ binstart,
                           int* __restrict__ chunkoff){
  __shared__ int s[NCHUNK];
  int b = blockIdx.x, c = threadIdx.x;
  int v = cnt[c*NBIN + b];
  s[c] = v;
  __syncthreads();
  for (int off = 1; off < NCHUNK; off <<= 1){
    int u = (c >= off) ? s[c - off] : 0;
    __syncthreads();
    s[c] += u;
    __syncthreads();
  }
  chunkoff[c*NBIN + b] = binstart[b] + s[c] - v;
}

__global__ void k_binscatter(const int* __restrict__ src, const int* __restrict__ dst,
                             const int* __restrict__ chunkoff, u32* __restrict__ rec){
  __shared__ int cur[NBIN];
  int t = threadIdx.x;
  for (int i = t; i < NBIN; i += 256) cur[i] = chunkoff[blockIdx.x*NBIN + i];
  __syncthreads();
  int base = blockIdx.x*CHUNK;
  int end  = min(base + CHUNK, N_EDGES);
  for (int i = base + t; i < end; i += 256){
    int d = dst[i], sv = src[i];
    int b = d >> 7;
    int p = atomicAdd(&cur[b], 1);
    rec[p] = (u32)(((d & 127) << 16) | sv);
  }
}

__global__ void k_bincsr(const u32* __restrict__ rec, const int* __restrict__ binstart,
                         int* __restrict__ rowptr, float* __restrict__ dinv,
                         int* __restrict__ col){
  __shared__ u32 recs[MAXBIN];
  __shared__ int colL[MAXBIN];
  __shared__ int deg[BINSZ];
  __shared__ int cursor[BINSZ];
  __shared__ int sc[BINSZ];
  int b = blockIdx.x, t = threadIdx.x;
  int s0 = binstart[b], e0 = binstart[b+1];
  int n = e0 - s0;
  if (t < BINSZ) deg[t] = 0;
  for (int i = t; i < n; i += 256) recs[i] = rec[s0 + i];
  __syncthreads();
  for (int i = t; i < n; i += 256) atomicAdd(&deg[(recs[i] >> 16) & 127], 1);
  __syncthreads();
  if (t < BINSZ) sc[t] = deg[t];
  __syncthreads();
  for (int off = 1; off < BINSZ; off <<= 1){
    int u = 0;
    if (t < BINSZ && t >= off) u = sc[t - off];
    __syncthreads();
    if (t < BINSZ) sc[t] += u;
    __syncthreads();
  }
  if (t < BINSZ){
    int pref = sc[t] - deg[t];
    cursor[t] = pref;
    int node = b*BINSZ + t;
    if (node < N_NODES){
      rowptr[node] = s0 + pref;
      dinv[node] = 1.0f / (float)max(deg[t], 1);
    }
  }
  __syncthreads();
  for (int i = t; i < n; i += 256){
    u32 r = recs[i];
    int p = atomicAdd(&cursor[(r >> 16) & 127], 1);
    colL[p] = (int)(r & 0xFFFFu);
  }
  __syncthreads();
  for (int i = t; i < n; i += 256) col[s0 + i] = colL[i];
}

// ---- prep kernels -----------------------------------------------------------
__global__ void k_cast(const float4* __restrict__ x, uint2* __restrict__ out){
  int i = blockIdx.x*blockDim.x + threadIdx.x;
  if (i < N_NODES*128/4){
    float4 v = x[i];
    out[i] = make_uint2(pack2(v.x, v.y), pack2(v.z, v.w));
  }
}

// wcat[l]: [256 n][128 k] bf16, 16B chunks XOR-swizzled (c ^= n&15).
__global__ void k_prepw(const float* __restrict__ Wrel1, const float* __restrict__ Wroot1,
                        const float* __restrict__ Wrel2, const float* __restrict__ Wroot2,
                        const float* __restrict__ Wrel3, const float* __restrict__ Wroot3,
                        u16* __restrict__ wcat){
  int id = blockIdx.x*blockDim.x + threadIdx.x;
  if (id >= 3*256*128) return;
  int l = id >> 15;
  int r = id & 32767;
  int n = r >> 7;
  int k = r & 127;
  const float* Wrel  = (l==0) ? Wrel1  : (l==1) ? Wrel2  : Wrel3;
  const float* Wroot = (l==0) ? Wroot1 : (l==1) ? Wroot2 : Wroot3;
  float w = (n < 128) ? Wrel[k*128 + n] : Wroot[k*128 + (n - 128)];
  int c = k >> 3, j = k & 7;
  wcat[l*32768 + n*128 + ((c ^ (n & 15)) << 3) + j] = f2b(w);
}

// W1,W2 -> bf16 [n(128)][k(128)] plain (B-operand read straight from global)
__global__ void k_prepmlp(const float* __restrict__ W1, const float* __restrict__ W2,
                          u16* __restrict__ wm){
  int id = blockIdx.x*blockDim.x + threadIdx.x;
  if (id >= 2*128*128) return;
  int l = id >> 14;
  int r = id & 16383;
  int n = r >> 7;
  int k = r & 127;
  const float* W = l ? W2 : W1;
  wm[l*16384 + n*128 + k] = f2b(W[k*128 + n]);
}

// ---- GEMM: [Y|Z] = A(bf16) @ [Wrel|Wroot]  (M=50000, K=128, N=256) ---------
__launch_bounds__(256, 2)
__global__ void k_gemm(const u16* __restrict__ A, const u16* __restrict__ Wcat,
                       u16* __restrict__ Y, float* __restrict__ Z){
  __shared__ u16 Bs[256*128];
  {
    const uint4* s = (const uint4*)Wcat;
    uint4* d = (uint4*)Bs;
    #pragma unroll
    for (int i = 0; i < 16; i++) d[threadIdx.x + 256*i] = s[threadIdx.x + 256*i];
  }
  __syncthreads();

  int wave = threadIdx.x >> 6, lane = threadIdx.x & 63;
  int l15 = lane & 15, quad = lane >> 4;
  int wy = wave >> 1, wx = wave & 1;
  int rowBase = blockIdx.x*128 + wy*64;

  floatx4 acc[4][8] = {};

  #pragma unroll
  for (int k0 = 0; k0 < 128; k0 += 32){
    int c = (k0 >> 3) + quad;
    short8 a[4];
    #pragma unroll
    for (int mt = 0; mt < 4; mt++){
      int row = rowBase + mt*16 + l15;
      if (row > N_NODES-1) row = N_NODES-1;   // clamp; stores are masked
      a[mt] = *(const short8*)(A + row*128 + k0 + quad*8);
    }
    #pragma unroll
    for (int nt = 0; nt < 8; nt++){
      int n = wx*128 + nt*16 + l15;
      short8 b = *(const short8*)(Bs + n*128 + ((c ^ (n & 15)) << 3));
      #pragma unroll
      for (int mt = 0; mt < 4; mt++)
        acc[mt][nt] = __builtin_amdgcn_mfma_f32_16x16x32_bf16(a[mt], b, acc[mt][nt], 0, 0, 0);
    }
  }

  #pragma unroll
  for (int mt = 0; mt < 4; mt++){
    int rbase = rowBase + mt*16 + quad*4;
    #pragma unroll
    for (int r = 0; r < 4; r++){
      int row = rbase + r;
      if (row < N_NODES){
        #pragma unroll
        for (int nt = 0; nt < 8; nt++){
          int coln = nt*16 + l15;
          float v = acc[mt][nt][r];
          if (wx == 0) Y[row*128 + coln] = f2b(v);
          else         Z[row*128 + coln] = v;
        }
      }
    }
  }
}

// ---- Aggregation ------------------------------------------------------------
__global__ void k_agg(const u16* __restrict__ Y, const float* __restrict__ Z,
                      const int* __restrict__ rowptr, const int* __restrict__ col,
                      const float* __restrict__ dinv, const float* __restrict__ brel,
                      u16* __restrict__ Xout, int do_relu){
  int wave = threadIdx.x >> 6, lane = threadIdx.x & 63;
  int node = blockIdx.x*4 + wave;
  if (node >= N_NODES) return;
  int s = rowptr[node], e = rowptr[node+1];
  const u32* Yu = (const u32*)Y;
  float s0 = 0.f, s1 = 0.f;
  for (int cb = s; cb < e; cb += 64){
    int cnt = min(64, e - cb);
    int idx = 0;
    if (cb + lane < e) idx = col[cb + lane];
    int k = 0;
    for (; k + 4 <= cnt; k += 4){
      int j0 = __shfl(idx, k),   j1 = __shfl(idx, k+1);
      int j2 = __shfl(idx, k+2), j3 = __shfl(idx, k+3);
      u32 v0 = Yu[j0*64 + lane], v1 = Yu[j1*64 + lane];
      u32 v2 = Yu[j2*64 + lane], v3 = Yu[j3*64 + lane];
      s0 += (blo(v0) + blo(v1)) + (blo(v2) + blo(v3));
      s1 += (bhi(v0) + bhi(v1)) + (bhi(v2) + bhi(v3));
    }
    for (; k < cnt; k++){
      int j = __shfl(idx, k);
      u32 v = Yu[j*64 + lane];
      s0 += blo(v); s1 += bhi(v);
    }
  }
  float di = dinv[node];
  float2 z  = *(const float2*)(Z + node*128 + 2*lane);
  float2 bb = *(const float2*)(brel + 2*lane);
  float h0 = fmaf(s0, di, bb.x + z.x);
  float h1 = fmaf(s1, di, bb.y + z.y);
  if (do_relu){ h0 = fmaxf(h0, 0.f); h1 = fmaxf(h1, 0.f); }
  ((u32*)Xout)[node*64 + lane] = pack2(h0, h1);
}

// ---- graph boundaries -------------------------------------------------------
__global__ void k_bounds(const int* __restrict__ batch, int* __restrict__ start){
  int g = threadIdx.x + blockIdx.x*blockDim.x;
  if (g > N_GRAPHS) return;
  int lo = 0, hi = N_NODES;
  while (lo < hi){ int mid = (lo + hi) >> 1; if (batch[mid] < g) lo = mid + 1; else hi = mid; }
  start[g] = lo;
}

// ---- mean pool: 1 block/graph, 4 waves stride nodes; out bf16 Gb[512][128] --
__global__ void k_pool(const u16* __restrict__ H3, const int* __restrict__ start,
                       u16* __restrict__ Gb){
  __shared__ float2 part[4][64];
  int gid = blockIdx.x;
  int wave = threadIdx.x >> 6, lane = threadIdx.x & 63;
  int s = start[gid], e = start[gid+1];
  const u32* Hu = (const u32*)H3;
  float a0 = 0.f, a1 = 0.f;
  for (int i = s + wave; i < e; i += 4){
    u32 v = Hu[i*64 + lane];
    a0 += blo(v); a1 += bhi(v);
  }
  part[wave][lane] = make_float2(a0, a1);
  __syncthreads();
  if (wave == 0){
    float inv = 1.0f / (float)max(e - s, 1);
    float2 p0 = part[0][lane], p1 = part[1][lane];
    float2 p2 = part[2][lane], p3 = part[3][lane];
    float g0 = ((p0.x + p1.x) + (p2.x + p3.x)) * inv;
    float g1 = ((p0.y + p1.y) + (p2.y + p3.y)) * inv;
    ((u32*)Gb)[gid*64 + lane] = pack2(g0, g1);
  }
}

// ---- fused MLP: G[512,128] @W1 relu @W2 relu @Wo + biases -------------------
// 4 blocks x 128 graphs. Layers 1-2: bf16 MFMA, B-frags straight from global
// (L2-hot), h round-trips through padded LDS (C-layout -> A-layout). Layer 3 f32.
#define APAD 136
__launch_bounds__(256)
__global__ void k_mlp(const u16* __restrict__ Gb, const u16* __restrict__ wm,
                      const float* __restrict__ b1, const float* __restrict__ b2,
                      const float* __restrict__ Wo, const float* __restrict__ bo,
                      float* __restrict__ out){
  __shared__ u16 Apad[128*APAD];
  int t = threadIdx.x;
  int wave = t >> 6, lane = t & 63;
  int l15 = lane & 15, quad = lane >> 4;
  int R = blockIdx.x*128;

  // ---- layer 1: A from global Gb, B from global wm[0] ----
  floatx4 acc[2][8] = {};
  #pragma unroll
  for (int k0 = 0; k0 < 128; k0 += 32){
    short8 a[2];
    #pragma unroll
    for (int mt = 0; mt < 2; mt++){
      int row = R + (wave*2 + mt)*16 + l15;
      a[mt] = *(const short8*)(Gb + row*128 + k0 + quad*8);
    }
    #pragma unroll
    for (int nt = 0; nt < 8; nt++){
      int n = nt*16 + l15;
      short8 b = *(const short8*)(wm + n*128 + k0 + quad*8);
      #pragma unroll
      for (int mt = 0; mt < 2; mt++)
        acc[mt][nt] = __builtin_amdgcn_mfma_f32_16x16x32_bf16(a[mt], b, acc[mt][nt], 0, 0, 0);
    }
  }
  #pragma unroll
  for (int nt = 0; nt < 8; nt++){
    int coln = nt*16 + l15;
    float bc = b1[coln];
    #pragma unroll
    for (int mt = 0; mt < 2; mt++){
      int lmb = (wave*2 + mt)*16 + quad*4;
      #pragma unroll
      for (int r = 0; r < 4; r++)
        Apad[(lmb + r)*APAD + coln] = f2b(fmaxf(acc[mt][nt][r] + bc, 0.f));
    }
  }
  __syncthreads();

  // ---- layer 2: A from LDS, B from global wm[1] ----
  floatx4 acc2[2][8] = {};
  #pragma unroll
  for (int k0 = 0; k0 < 128; k0 += 32){
    short8 a[2];
    #pragma unroll
    for (int mt = 0; mt < 2; mt++){
      int lm = (wave*2 + mt)*16 + l15;
      a[mt] = *(const short8*)(Apad + lm*APAD + k0 + quad*8);
    }
    #pragma unroll
    for (int nt = 0; nt < 8; nt++){
      int n = nt*16 + l15;
      short8 b = *(const short8*)(wm + 16384 + n*128 + k0 + quad*8);
      #pragma unroll
      for (int mt = 0; mt < 2; mt++)
        acc2[mt][nt] = __builtin_amdgcn_mfma_f32_16x16x32_bf16(a[mt], b, acc2[mt][nt], 0, 0, 0);
    }
  }
  __syncthreads();   // all A reads done before overwrite
  #pragma unroll
  for (int nt = 0; nt < 8; nt++){
    int coln = nt*16 + l15;
    float bc = b2[coln];
    #pragma unroll
    for (int mt = 0; mt < 2; mt++){
      int lmb = (wave*2 + mt)*16 + quad*4;
      #pragma unroll
      for (int r = 0; r < 4; r++)
        Apad[(lmb + r)*APAD + coln] = f2b(fmaxf(acc2[mt][nt][r] + bc, 0.f));
    }
  }
  __syncthreads();

  // ---- layer 3: h2[128] @ Wo[128x8] + bo, f32 vector ----
  int row = t >> 1;
  int c0  = (t & 1)*4;
  float o0 = bo[c0], o1 = bo[c0+1], o2 = bo[c0+2], o3 = bo[c0+3];
  for (int k = 0; k < 128; k++){
    float h = b2f(Apad[row*APAD + k]);
    const float* w = Wo + k*8 + c0;
    o0 = fmaf(h, w[0], o0); o1 = fmaf(h, w[1], o1);
    o2 = fmaf(h, w[2], o2); o3 = fmaf(h, w[3], o3);
  }
  float* op = out + (R + row)*8 + c0;
  op[0] = o0; op[1] = o1; op[2] = o2; op[3] = o3;
}

extern "C" void kernel_launch(void* const* d_in, const int* in_sizes, int n_in,
                              void* d_out, int out_size, void* d_ws, size_t ws_size,
                              hipStream_t stream){
  const float* x     = (const float*)d_in[0];
  const int*   ei    = (const int*)d_in[1];
  const int*   batch = (const int*)d_in[2];
  const float* Wrel[3]  = {(const float*)d_in[3], (const float*)d_in[6], (const float*)d_in[9]};
  const float* brel[3]  = {(const float*)d_in[4], (const float*)d_in[7], (const float*)d_in[10]};
  const float* Wroot[3] = {(const float*)d_in[5], (const float*)d_in[8], (const float*)d_in[11]};
  const float* W1 = (const float*)d_in[12]; const float* b1 = (const float*)d_in[13];
  const float* W2 = (const float*)d_in[14]; const float* b2 = (const float*)d_in[15];
  const float* Wo = (const float*)d_in[16]; const float* bo = (const float*)d_in[17];
  const int* esrc = ei;
  const int* edst = ei + N_EDGES;

  char* ws = (char*)d_ws;
  size_t off = 0;
  auto alloc = [&](size_t bytes)->char*{
    char* p = ws + off; off += (bytes + 255) & ~(size_t)255; return p;
  };
  u16*   Y      = (u16*)  alloc((size_t)N_NODES*128*2);
  float* Z      = (float*)alloc((size_t)N_NODES*128*4);
  u16*   XA     = (u16*)  alloc((size_t)N_NODES*128*2);
  u16*   XB     = (u16*)  alloc((size_t)N_NODES*128*2);
  u16*   wcat   = (u16*)  alloc((size_t)3*256*128*2);
  u16*   wm     = (u16*)  alloc((size_t)2*128*128*2);
  u16*   Gb     = (u16*)  alloc((size_t)N_GRAPHS*128*2);
  int*   rowptr = (int*)  alloc((size_t)(N_NODES+1)*4);
  float* dinv   = (float*)alloc((size_t)N_NODES*4);
  int*   colIdx = (int*)  alloc((size_t)N_EDGES*4);   // doubles as rec buffer
  int*   start  = (int*)  alloc((size_t)(N_GRAPHS+1)*4);
  int*   cnt    = (int*)  alloc((size_t)NCHUNK*NBIN*4);
  int*   coff   = (int*)  alloc((size_t)NCHUNK*NBIN*4);
  int*   btot   = (int*)  alloc((size_t)NBIN*4);
  int*   bstart = (int*)  alloc((size_t)(NBIN+1)*4);
  u32*   rec    = (u32*)colIdx;

  hipMemsetAsync(btot, 0, (size_t)NBIN*4, stream);

  dim3 b256(256);
  k_binhist   <<<NCHUNK, b256, 0, stream>>>(edst, cnt, btot);
  k_binstart  <<<1, 512, 0, stream>>>(btot, bstart, rowptr);
  k_chunkoff  <<<NBIN, NCHUNK, 0, stream>>>(cnt, bstart, coff);
  k_binscatter<<<NCHUNK, b256, 0, stream>>>(esrc, edst, coff, rec);
  k_bincsr    <<<NBIN, b256, 0, stream>>>(rec, bstart, rowptr, dinv, colIdx);
  k_cast      <<<(N_NODES*128/4+255)/256, b256, 0, stream>>>((const float4*)x, (uint2*)XA);
  k_prepw     <<<(3*256*128+255)/256, b256, 0, stream>>>(Wrel[0],Wroot[0],Wrel[1],Wroot[1],
                                                         Wrel[2],Wroot[2], wcat);
  k_prepmlp   <<<(2*128*128+255)/256, b256, 0, stream>>>(W1, W2, wm);
  k_bounds    <<<3, 256, 0, stream>>>(batch, start);

  const int ggrid = (N_NODES + 127)/128;   // 391
  const int agrid = (N_NODES + 3)/4;       // 12500

  k_gemm<<<ggrid, b256, 0, stream>>>(XA, wcat + 0*32768, Y, Z);
  k_agg <<<agrid, b256, 0, stream>>>(Y, Z, rowptr, colIdx, dinv, brel[0], XB, 1);

  k_gemm<<<ggrid, b256, 0, stream>>>(XB, wcat + 1*32768, Y, Z);
  k_agg <<<agrid, b256, 0, stream>>>(Y, Z, rowptr, colIdx, dinv, brel[1], XA, 1);

  k_gemm<<<ggrid, b256, 0, stream>>>(XA, wcat + 2*32768, Y, Z);
  k_agg <<<agrid, b256, 0, stream>>>(Y, Z, rowptr, colIdx, dinv, brel[2], XB, 0);

  k_pool<<<N_GRAPHS, b256, 0, stream>>>(XB, start, Gb);
  k_mlp <<<4, b256, 0, stream>>>(Gb, wm, b1, b2, Wo, bo, (float*)d_out);
}

// Round 5
// 310.116 us; speedup vs baseline: 1.6269x; 1.0742x over previous
//
#include <hip/hip_runtime.h>
#include <hip/hip_bf16.h>
#include <stdint.h>

#define N_NODES  50000
#define N_EDGES  800000
#define N_GRAPHS 512

#define BINSZ   128
#define NBIN    ((N_NODES + BINSZ - 1)/BINSZ)    // 391
#define NCHUNK  256
#define CHUNK   ((N_EDGES + NCHUNK - 1)/NCHUNK)  // 3125
#define MAXBIN  3072

typedef __attribute__((ext_vector_type(8))) short  short8;
typedef __attribute__((ext_vector_type(4))) float  floatx4;
typedef unsigned short u16;
typedef unsigned int   u32;

__device__ __forceinline__ u16 f2b(float f){
  u32 u = __float_as_uint(f);
  u = (u + 0x7FFFu + ((u >> 16) & 1u)) >> 16;   // RNE
  return (u16)u;
}
__device__ __forceinline__ u32 pack2(float a, float b){
  return (u32)f2b(a) | ((u32)f2b(b) << 16);
}
__device__ __forceinline__ float blo(u32 v){ return __uint_as_float(v << 16); }
__device__ __forceinline__ float bhi(u32 v){ return __uint_as_float(v & 0xFFFF0000u); }
__device__ __forceinline__ float b2f(u16 s){ return __uint_as_float(((u32)s) << 16); }

// ---- CSR build via 2-level binning -----------------------------------------
__global__ void k_binhist(const int* __restrict__ dst, int* __restrict__ cnt,
                          int* __restrict__ bintotal){
  __shared__ int h[NBIN];
  int t = threadIdx.x;
  for (int i = t; i < NBIN; i += 256) h[i] = 0;
  __syncthreads();
  int base = blockIdx.x*CHUNK;
  int end  = min(base + CHUNK, N_EDGES);
  for (int i = base + t; i < end; i += 256) atomicAdd(&h[dst[i] >> 7], 1);
  __syncthreads();
  for (int i = t; i < NBIN; i += 256){
    cnt[blockIdx.x*NBIN + i] = h[i];
    if (h[i]) atomicAdd(&bintotal[i], h[i]);
  }
}

__global__ void k_binstart(const int* __restrict__ bintotal, int* __restrict__ binstart,
                           int* __restrict__ rowptr){
  __shared__ int s[512];
  int t = threadIdx.x;
  int v = (t < NBIN) ? bintotal[t] : 0;
  s[t] = v;
  __syncthreads();
  for (int off = 1; off < 512; off <<= 1){
    int u = (t >= off) ? s[t - off] : 0;
    __syncthreads();
    s[t] += u;
    __syncthreads();
  }
  if (t < NBIN) binstart[t] = s[t] - v;
  if (t == 0){ binstart[NBIN] = N_EDGES; rowptr[N_NODES] = N_EDGES; }
}

__global__ void k_chunkoff(const int* __restrict__ cnt, const int* __restrict__ binstart,
                           int* __restrict__ chunkoff){
  __shared__ int s[NCHUNK];
  int b = blockIdx.x, c = threadIdx.x;
  int v = cnt[c*NBIN + b];
  s[c] = v;
  __syncthreads();
  for (int off = 1; off < NCHUNK; off <<= 1){
    int u = (c >= off) ? s[c - off] : 0;
    __syncthreads();
    s[c] += u;
    __syncthreads();
  }
  chunkoff[c*NBIN + b] = binstart[b] + s[c] - v;
}

__global__ void k_binscatter(const int* __restrict__ src, const int* __restrict__ dst,
                             const int* __restrict__ chunkoff, u32* __restrict__ rec){
  __shared__ int cur[NBIN];
  int t = threadIdx.x;
  for (int i = t; i < NBIN; i += 256) cur[i] = chunkoff[blockIdx.x*NBIN + i];
  __syncthreads();
  int base = blockIdx.x*CHUNK;
  int end  = min(base + CHUNK, N_EDGES);
  for (int i = base + t; i < end; i += 256){
    int d = dst[i], sv = src[i];
    int b = d >> 7;
    int p = atomicAdd(&cur[b], 1);
    rec[p] = (u32)(((d & 127) << 16) | sv);
  }
}

__global__ void k_bincsr(const u32* __restrict__ rec, const int* __restrict__ binstart,
                         int* __restrict__ rowptr, float* __restrict__ dinv,
                         int* __restrict__ col){
  __shared__ u32 recs[MAXBIN];
  __shared__ int colL[MAXBIN];
  __shared__ int deg[BINSZ];
  __shared__ int cursor[BINSZ];
  __shared__ int sc[BINSZ];
  int b = blockIdx.x, t = threadIdx.x;
  int s0 = binstart[b], e0 = binstart[b+1];
  int n = e0 - s0;
  if (t < BINSZ) deg[t] = 0;
  for (int i = t; i < n; i += 256) recs[i] = rec[s0 + i];
  __syncthreads();
  for (int i = t; i < n; i += 256) atomicAdd(&deg[(recs[i] >> 16) & 127], 1);
  __syncthreads();
  if (t < BINSZ) sc[t] = deg[t];
  __syncthreads();
  for (int off = 1; off < BINSZ; off <<= 1){
    int u = 0;
    if (t < BINSZ && t >= off) u = sc[t - off];
    __syncthreads();
    if (t < BINSZ) sc[t] += u;
    __syncthreads();
  }
  if (t < BINSZ){
    int pref = sc[t] - deg[t];
    cursor[t] = pref;
    int node = b*BINSZ + t;
    if (node < N_NODES){
      rowptr[node] = s0 + pref;
      dinv[node] = 1.0f / (float)max(deg[t], 1);
    }
  }
  __syncthreads();
  for (int i = t; i < n; i += 256){
    u32 r = recs[i];
    int p = atomicAdd(&cursor[(r >> 16) & 127], 1);
    colL[p] = (int)(r & 0xFFFFu);
  }
  __syncthreads();
  for (int i = t; i < n; i += 256) col[s0 + i] = colL[i];
}

// ---- prep kernels -----------------------------------------------------------
__global__ void k_cast(const float4* __restrict__ x, uint2* __restrict__ out){
  int i = blockIdx.x*blockDim.x + threadIdx.x;
  if (i < N_NODES*128/4){
    float4 v = x[i];
    out[i] = make_uint2(pack2(v.x, v.y), pack2(v.z, v.w));
  }
}

// wcat2[l]: [128 n][256 k] bf16 ([Wrel;Wroot] stacked in k), 16B chunks
// XOR-swizzled (c ^= n&15, c in 0..31). Layers 1,2 only.
__global__ void k_prepw2(const float* __restrict__ Wrel1, const float* __restrict__ Wroot1,
                         const float* __restrict__ Wrel2, const float* __restrict__ Wroot2,
                         u16* __restrict__ wcat){
  int id = blockIdx.x*blockDim.x + threadIdx.x;
  if (id >= 2*128*256) return;
  int l = id >> 15;
  int r = id & 32767;
  int n = r >> 8;
  int k = r & 255;
  const float* Wrel  = l ? Wrel2  : Wrel1;
  const float* Wroot = l ? Wroot2 : Wroot1;
  float w = (k < 128) ? Wrel[k*128 + n] : Wroot[(k-128)*128 + n];
  int c = k >> 3, j = k & 7;
  wcat[l*32768 + n*256 + ((c ^ (n & 15)) << 3) + j] = f2b(w);
}

// W1,W2 -> bf16 [n(128)][k(128)] plain
__global__ void k_prepmlp(const float* __restrict__ W1, const float* __restrict__ W2,
                          u16* __restrict__ wm){
  int id = blockIdx.x*blockDim.x + threadIdx.x;
  if (id >= 2*128*128) return;
  int l = id >> 14;
  int r = id & 16383;
  int n = r >> 7;
  int k = r & 127;
  const float* W = l ? W2 : W1;
  wm[l*16384 + n*128 + k] = f2b(W[k*128 + n]);
}

// ---- Aggregation: M[i] = dinv[i] * sum_{j in N(i)} X[j]  (bf16 out) --------
__global__ void k_aggm(const u16* __restrict__ X, const int* __restrict__ rowptr,
                       const int* __restrict__ col, const float* __restrict__ dinv,
                       u16* __restrict__ M){
  int wave = threadIdx.x >> 6, lane = threadIdx.x & 63;
  int node = blockIdx.x*4 + wave;
  if (node >= N_NODES) return;
  int s = rowptr[node], e = rowptr[node+1];
  const u32* Xu = (const u32*)X;
  float s0 = 0.f, s1 = 0.f;
  for (int cb = s; cb < e; cb += 64){
    int cnt = min(64, e - cb);
    int idx = 0;
    if (cb + lane < e) idx = col[cb + lane];
    int k = 0;
    for (; k + 4 <= cnt; k += 4){
      int j0 = __shfl(idx, k),   j1 = __shfl(idx, k+1);
      int j2 = __shfl(idx, k+2), j3 = __shfl(idx, k+3);
      u32 v0 = Xu[j0*64 + lane], v1 = Xu[j1*64 + lane];
      u32 v2 = Xu[j2*64 + lane], v3 = Xu[j3*64 + lane];
      s0 += (blo(v0) + blo(v1)) + (blo(v2) + blo(v3));
      s1 += (bhi(v0) + bhi(v1)) + (bhi(v2) + bhi(v3));
    }
    for (; k < cnt; k++){
      int j = __shfl(idx, k);
      u32 v = Xu[j*64 + lane];
      s0 += blo(v); s1 += bhi(v);
    }
  }
  float di = dinv[node];
  ((u32*)M)[node*64 + lane] = pack2(s0*di, s1*di);
}

// ---- GEMM: Xout = relu([M|X] @ Wcat2 + brel)  (M=50000, K=256, N=128) ------
__launch_bounds__(256, 2)
__global__ void k_gemm2(const u16* __restrict__ M, const u16* __restrict__ X,
                        const u16* __restrict__ Wcat, const float* __restrict__ brel,
                        u16* __restrict__ Xout){
  __shared__ u16 Bs[128*256];
  {
    const uint4* s = (const uint4*)Wcat;
    uint4* d = (uint4*)Bs;
    #pragma unroll
    for (int i = 0; i < 16; i++) d[threadIdx.x + 256*i] = s[threadIdx.x + 256*i];
  }
  __syncthreads();

  int wave = threadIdx.x >> 6, lane = threadIdx.x & 63;
  int l15 = lane & 15, quad = lane >> 4;
  int wy = wave >> 1, wx = wave & 1;
  int rowBase = blockIdx.x*128 + wy*64;

  floatx4 acc[4][4] = {};

  #pragma unroll
  for (int k0 = 0; k0 < 256; k0 += 32){
    const u16* Asrc = (k0 < 128) ? M : X;
    int kk = k0 & 127;
    int c = (k0 >> 3) + quad;
    short8 a[4];
    #pragma unroll
    for (int mt = 0; mt < 4; mt++){
      int row = rowBase + mt*16 + l15;
      if (row > N_NODES-1) row = N_NODES-1;   // clamp; stores are masked
      a[mt] = *(const short8*)(Asrc + row*128 + kk + quad*8);
    }
    #pragma unroll
    for (int nt = 0; nt < 4; nt++){
      int n = wx*64 + nt*16 + l15;
      short8 b = *(const short8*)(Bs + n*256 + ((c ^ (n & 15)) << 3));
      #pragma unroll
      for (int mt = 0; mt < 4; mt++)
        acc[mt][nt] = __builtin_amdgcn_mfma_f32_16x16x32_bf16(a[mt], b, acc[mt][nt], 0, 0, 0);
    }
  }

  float bc[4];
  #pragma unroll
  for (int nt = 0; nt < 4; nt++) bc[nt] = brel[wx*64 + nt*16 + l15];

  #pragma unroll
  for (int mt = 0; mt < 4; mt++){
    int rbase = rowBase + mt*16 + quad*4;
    #pragma unroll
    for (int r = 0; r < 4; r++){
      int row = rbase + r;
      if (row < N_NODES){
        #pragma unroll
        for (int nt = 0; nt < 4; nt++){
          int n = wx*64 + nt*16 + l15;
          Xout[row*128 + n] = f2b(fmaxf(acc[mt][nt][r] + bc[nt], 0.f));
        }
      }
    }
  }
}

// ---- graph boundaries -------------------------------------------------------
__global__ void k_bounds(const int* __restrict__ batch, int* __restrict__ start){
  int g = threadIdx.x + blockIdx.x*blockDim.x;
  if (g > N_GRAPHS) return;
  int lo = 0, hi = N_NODES;
  while (lo < hi){ int mid = (lo + hi) >> 1; if (batch[mid] < g) lo = mid + 1; else hi = mid; }
  start[g] = lo;
}

// ---- pool M3 and X3 per graph (f32 out) ------------------------------------
__global__ void k_pool2(const u16* __restrict__ M3, const u16* __restrict__ X3,
                        const int* __restrict__ start,
                        float2* __restrict__ PM, float2* __restrict__ PX){
  __shared__ float2 pm[4][64], px[4][64];
  int gid = blockIdx.x;
  int wave = threadIdx.x >> 6, lane = threadIdx.x & 63;
  int s = start[gid], e = start[gid+1];
  const u32* Mu = (const u32*)M3;
  const u32* Xu = (const u32*)X3;
  float m0 = 0.f, m1 = 0.f, x0 = 0.f, x1 = 0.f;
  for (int i = s + wave; i < e; i += 4){
    u32 vm = Mu[i*64 + lane];
    u32 vx = Xu[i*64 + lane];
    m0 += blo(vm); m1 += bhi(vm);
    x0 += blo(vx); x1 += bhi(vx);
  }
  pm[wave][lane] = make_float2(m0, m1);
  px[wave][lane] = make_float2(x0, x1);
  __syncthreads();
  if (wave == 0){
    float inv = 1.0f / (float)max(e - s, 1);
    float2 a0 = pm[0][lane], a1 = pm[1][lane], a2 = pm[2][lane], a3 = pm[3][lane];
    float2 b0 = px[0][lane], b1 = px[1][lane], b2 = px[2][lane], b3 = px[3][lane];
    PM[gid*64 + lane] = make_float2(((a0.x+a1.x)+(a2.x+a3.x))*inv,
                                    ((a0.y+a1.y)+(a2.y+a3.y))*inv);
    PX[gid*64 + lane] = make_float2(((b0.x+b1.x)+(b2.x+b3.x))*inv,
                                    ((b0.y+b1.y)+(b2.y+b3.y))*inv);
  }
}

// ---- conv3 on pooled values: Gb = PM@Wrel3 + PX@Wroot3 + brel3 (f32 math) --
__global__ void k_conv3(const float* __restrict__ PM, const float* __restrict__ PX,
                        const float* __restrict__ Wrel, const float* __restrict__ Wroot,
                        const float* __restrict__ brel, u16* __restrict__ Gb){
  __shared__ float pmS[2][128], pxS[2][128];
  int t = threadIdx.x;
  int g0 = blockIdx.x*2;
  pmS[t >> 7][t & 127] = PM[g0*128 + t];
  pxS[t >> 7][t & 127] = PX[g0*128 + t];
  __syncthreads();
  int g = t >> 7, n = t & 127;
  float a = brel[n];
  for (int k = 0; k < 128; k++){
    a = fmaf(pmS[g][k], Wrel[k*128 + n], a);
    a = fmaf(pxS[g][k], Wroot[k*128 + n], a);
  }
  Gb[(g0 + g)*128 + n] = f2b(a);
}

// ---- fused MLP: Gb[512,128] @W1 relu @W2 relu @Wo + biases ------------------
#define APAD 136
__launch_bounds__(256)
__global__ void k_mlp(const u16* __restrict__ Gb, const u16* __restrict__ wm,
                      const float* __restrict__ b1, const float* __restrict__ b2,
                      const float* __restrict__ Wo, const float* __restrict__ bo,
                      float* __restrict__ out){
  __shared__ u16 Apad[128*APAD];
  int t = threadIdx.x;
  int wave = t >> 6, lane = t & 63;
  int l15 = lane & 15, quad = lane >> 4;
  int R = blockIdx.x*128;

  floatx4 acc[2][8] = {};
  #pragma unroll
  for (int k0 = 0; k0 < 128; k0 += 32){
    short8 a[2];
    #pragma unroll
    for (int mt = 0; mt < 2; mt++){
      int row = R + (wave*2 + mt)*16 + l15;
      a[mt] = *(const short8*)(Gb + row*128 + k0 + quad*8);
    }
    #pragma unroll
    for (int nt = 0; nt < 8; nt++){
      int n = nt*16 + l15;
      short8 b = *(const short8*)(wm + n*128 + k0 + quad*8);
      #pragma unroll
      for (int mt = 0; mt < 2; mt++)
        acc[mt][nt] = __builtin_amdgcn_mfma_f32_16x16x32_bf16(a[mt], b, acc[mt][nt], 0, 0, 0);
    }
  }
  #pragma unroll
  for (int nt = 0; nt < 8; nt++){
    int coln = nt*16 + l15;
    float bc = b1[coln];
    #pragma unroll
    for (int mt = 0; mt < 2; mt++){
      int lmb = (wave*2 + mt)*16 + quad*4;
      #pragma unroll
      for (int r = 0; r < 4; r++)
        Apad[(lmb + r)*APAD + coln] = f2b(fmaxf(acc[mt][nt][r] + bc, 0.f));
    }
  }
  __syncthreads();

  floatx4 acc2[2][8] = {};
  #pragma unroll
  for (int k0 = 0; k0 < 128; k0 += 32){
    short8 a[2];
    #pragma unroll
    for (int mt = 0; mt < 2; mt++){
      int lm = (wave*2 + mt)*16 + l15;
      a[mt] = *(const short8*)(Apad + lm*APAD + k0 + quad*8);
    }
    #pragma unroll
    for (int nt = 0; nt < 8; nt++){
      int n = nt*16 + l15;
      short8 b = *(const short8*)(wm + 16384 + n*128 + k0 + quad*8);
      #pragma unroll
      for (int mt = 0; mt < 2; mt++)
        acc2[mt][nt] = __builtin_amdgcn_mfma_f32_16x16x32_bf16(a[mt], b, acc2[mt][nt], 0, 0, 0);
    }
  }
  __syncthreads();
  #pragma unroll
  for (int nt = 0; nt < 8; nt++){
    int coln = nt*16 + l15;
    float bc = b2[coln];
    #pragma unroll
    for (int mt = 0; mt < 2; mt++){
      int lmb = (wave*2 + mt)*16 + quad*4;
      #pragma unroll
      for (int r = 0; r < 4; r++)
        Apad[(lmb + r)*APAD + coln] = f2b(fmaxf(acc2[mt][nt][r] + bc, 0.f));
    }
  }
  __syncthreads();

  int row = t >> 1;
  int c0  = (t & 1)*4;
  float o0 = bo[c0], o1 = bo[c0+1], o2 = bo[c0+2], o3 = bo[c0+3];
  for (int k = 0; k < 128; k++){
    float h = b2f(Apad[row*APAD + k]);
    const float* w = Wo + k*8 + c0;
    o0 = fmaf(h, w[0], o0); o1 = fmaf(h, w[1], o1);
    o2 = fmaf(h, w[2], o2); o3 = fmaf(h, w[3], o3);
  }
  float* op = out + (R + row)*8 + c0;
  op[0] = o0; op[1] = o1; op[2] = o2; op[3] = o3;
}

extern "C" void kernel_launch(void* const* d_in, const int* in_sizes, int n_in,
                              void* d_out, int out_size, void* d_ws, size_t ws_size,
                              hipStream_t stream){
  const float* x     = (const float*)d_in[0];
  const int*   ei    = (const int*)d_in[1];
  const int*   batch = (const int*)d_in[2];
  const float* Wrel1 = (const float*)d_in[3];
  const float* brel1 = (const float*)d_in[4];
  const float* Wroot1= (const float*)d_in[5];
  const float* Wrel2 = (const float*)d_in[6];
  const float* brel2 = (const float*)d_in[7];
  const float* Wroot2= (const float*)d_in[8];
  const float* Wrel3 = (const float*)d_in[9];
  const float* brel3 = (const float*)d_in[10];
  const float* Wroot3= (const float*)d_in[11];
  const float* W1 = (const float*)d_in[12]; const float* b1 = (const float*)d_in[13];
  const float* W2 = (const float*)d_in[14]; const float* b2 = (const float*)d_in[15];
  const float* Wo = (const float*)d_in[16]; const float* bo = (const float*)d_in[17];
  const int* esrc = ei;
  const int* edst = ei + N_EDGES;

  char* ws = (char*)d_ws;
  size_t off = 0;
  auto alloc = [&](size_t bytes)->char*{
    char* p = ws + off; off += (bytes + 255) & ~(size_t)255; return p;
  };
  u16*   X1     = (u16*)  alloc((size_t)N_NODES*128*2);
  u16*   X2     = (u16*)  alloc((size_t)N_NODES*128*2);
  u16*   X3     = (u16*)  alloc((size_t)N_NODES*128*2);
  u16*   Mb     = (u16*)  alloc((size_t)N_NODES*128*2);
  u16*   wcat   = (u16*)  alloc((size_t)2*128*256*2);
  u16*   wm     = (u16*)  alloc((size_t)2*128*128*2);
  u16*   Gb     = (u16*)  alloc((size_t)N_GRAPHS*128*2);
  float* PM     = (float*)alloc((size_t)N_GRAPHS*128*4);
  float* PX     = (float*)alloc((size_t)N_GRAPHS*128*4);
  int*   rowptr = (int*)  alloc((size_t)(N_NODES+1)*4);
  float* dinv   = (float*)alloc((size_t)N_NODES*4);
  int*   colIdx = (int*)  alloc((size_t)N_EDGES*4);   // doubles as rec buffer
  int*   start  = (int*)  alloc((size_t)(N_GRAPHS+1)*4);
  int*   cnt    = (int*)  alloc((size_t)NCHUNK*NBIN*4);
  int*   coff   = (int*)  alloc((size_t)NCHUNK*NBIN*4);
  int*   btot   = (int*)  alloc((size_t)NBIN*4);
  int*   bstart = (int*)  alloc((size_t)(NBIN+1)*4);
  u32*   rec    = (u32*)colIdx;

  hipMemsetAsync(btot, 0, (size_t)NBIN*4, stream);

  dim3 b256(256);
  k_binhist   <<<NCHUNK, b256, 0, stream>>>(edst, cnt, btot);
  k_binstart  <<<1, 512, 0, stream>>>(btot, bstart, rowptr);
  k_chunkoff  <<<NBIN, NCHUNK, 0, stream>>>(cnt, bstart, coff);
  k_binscatter<<<NCHUNK, b256, 0, stream>>>(esrc, edst, coff, rec);
  k_bincsr    <<<NBIN, b256, 0, stream>>>(rec, bstart, rowptr, dinv, colIdx);
  k_cast      <<<(N_NODES*128/4+255)/256, b256, 0, stream>>>((const float4*)x, (uint2*)X1);
  k_prepw2    <<<(2*128*256+255)/256, b256, 0, stream>>>(Wrel1, Wroot1, Wrel2, Wroot2, wcat);
  k_prepmlp   <<<(2*128*128+255)/256, b256, 0, stream>>>(W1, W2, wm);
  k_bounds    <<<3, 256, 0, stream>>>(batch, start);

  const int ggrid = (N_NODES + 127)/128;   // 391
  const int agrid = (N_NODES + 3)/4;       // 12500

  k_aggm <<<agrid, b256, 0, stream>>>(X1, rowptr, colIdx, dinv, Mb);
  k_gemm2<<<ggrid, b256, 0, stream>>>(Mb, X1, wcat + 0*32768, brel1, X2);

  k_aggm <<<agrid, b256, 0, stream>>>(X2, rowptr, colIdx, dinv, Mb);
  k_gemm2<<<ggrid, b256, 0, stream>>>(Mb, X2, wcat + 1*32768, brel2, X3);

  k_aggm <<<agrid, b256, 0, stream>>>(X3, rowptr, colIdx, dinv, Mb);

  k_pool2<<<N_GRAPHS, b256, 0, stream>>>(Mb, X3, start, (float2*)PM, (float2*)PX);
  k_conv3<<<N_GRAPHS/2, b256, 0, stream>>>(PM, PX, Wrel3, Wroot3, brel3, Gb);
  k_mlp  <<<4, b256, 0, stream>>>(Gb, wm, b1, b2, Wo, bo, (float*)d_out);
}

// Round 6
// 282.281 us; speedup vs baseline: 1.7873x; 1.0986x over previous
//
#include <hip/hip_runtime.h>
#include <hip/hip_bf16.h>
#include <stdint.h>

#define N_NODES  50000
#define N_EDGES  800000
#define N_GRAPHS 512

#define BINSZ   128
#define NBIN    ((N_NODES + BINSZ - 1)/BINSZ)    // 391
#define NCHUNK  256
#define CHUNK   ((N_EDGES + NCHUNK - 1)/NCHUNK)  // 3125
#define MAXBIN  3072                             // per-bin capacity (mean 2048 + 22 sigma)

typedef __attribute__((ext_vector_type(8))) short  short8;
typedef __attribute__((ext_vector_type(4))) float  floatx4;
typedef unsigned short u16;
typedef unsigned int   u32;

__device__ __forceinline__ u16 f2b(float f){
  u32 u = __float_as_uint(f);
  u = (u + 0x7FFFu + ((u >> 16) & 1u)) >> 16;   // RNE
  return (u16)u;
}
__device__ __forceinline__ u32 pack2(float a, float b){
  return (u32)f2b(a) | ((u32)f2b(b) << 16);
}
__device__ __forceinline__ float blo(u32 v){ return __uint_as_float(v << 16); }
__device__ __forceinline__ float bhi(u32 v){ return __uint_as_float(v & 0xFFFF0000u); }
__device__ __forceinline__ float b2f(u16 s){ return __uint_as_float(((u32)s) << 16); }

// ---- fused prep: cast X, prep conv/mlp weights, graph bounds, bincur init ---
// grid sections by blockIdx.x:
//   [0,6250)      cast x -> bf16 X1          (1.6M float4 groups)
//   [6250,6506)   wcat2 layers 1,2           (65536 elems)
//   [6506,6634)   wm (W1,W2)                 (32768 elems)
//   [6634,6637)   graph bounds               (513)
//   [6637,6639)   bincur[b] = b*MAXBIN       (391)
#define PREP_CAST   6250
#define PREP_W2     (PREP_CAST + 256)
#define PREP_MLP    (PREP_W2 + 128)
#define PREP_BND    (PREP_MLP + 3)
#define PREP_CUR    (PREP_BND + 2)
__global__ void k_prep(const float4* __restrict__ x, uint2* __restrict__ X1,
                       const float* __restrict__ Wrel1, const float* __restrict__ Wroot1,
                       const float* __restrict__ Wrel2, const float* __restrict__ Wroot2,
                       u16* __restrict__ wcat,
                       const float* __restrict__ W1, const float* __restrict__ W2,
                       u16* __restrict__ wm,
                       const int* __restrict__ batch, int* __restrict__ start,
                       int* __restrict__ bincur){
  int blk = blockIdx.x, t = threadIdx.x;
  if (blk < PREP_CAST){
    int i = blk*256 + t;                       // exactly 1,600,000
    float4 v = x[i];
    X1[i] = make_uint2(pack2(v.x, v.y), pack2(v.z, v.w));
  } else if (blk < PREP_W2){
    int id = (blk - PREP_CAST)*256 + t;        // exactly 65536
    int l = id >> 15;
    int r = id & 32767;
    int n = r >> 8;
    int k = r & 255;
    const float* Wrel  = l ? Wrel2  : Wrel1;
    const float* Wroot = l ? Wroot2 : Wroot1;
    float w = (k < 128) ? Wrel[k*128 + n] : Wroot[(k-128)*128 + n];
    int c = k >> 3, j = k & 7;
    wcat[l*32768 + n*256 + ((c ^ (n & 15)) << 3) + j] = f2b(w);
  } else if (blk < PREP_MLP){
    int id = (blk - PREP_W2)*256 + t;          // exactly 32768
    int l = id >> 14;
    int r = id & 16383;
    int n = r >> 7;
    int k = r & 127;
    const float* W = l ? W2 : W1;
    wm[l*16384 + n*128 + k] = f2b(W[k*128 + n]);
  } else if (blk < PREP_BND){
    int g = (blk - PREP_MLP)*256 + t;
    if (g <= N_GRAPHS){
      int lo = 0, hi = N_NODES;
      while (lo < hi){ int mid = (lo + hi) >> 1; if (batch[mid] < g) lo = mid + 1; else hi = mid; }
      start[g] = lo;
    }
  } else {
    int i = (blk - PREP_BND)*256 + t;
    if (i < NBIN) bincur[i] = i*MAXBIN;
  }
}

// ---- CSR step 1: fused hist + range-reserve + scatter -----------------------
// Each block: LDS hist over bins, one global atomicAdd per (block,bin) to
// reserve a contiguous run in bin b's fixed segment [b*MAXBIN, ...), then
// scatter packed records (dstlocal<<16 | src).
__launch_bounds__(256)
__global__ void k_scatter2(const int* __restrict__ src, const int* __restrict__ dst,
                           int* __restrict__ bincur, u32* __restrict__ rec){
  __shared__ int h[NBIN];
  __shared__ int cur[NBIN];
  int t = threadIdx.x;
  for (int i = t; i < NBIN; i += 256) h[i] = 0;
  __syncthreads();
  int base = blockIdx.x*CHUNK;
  int end  = min(base + CHUNK, N_EDGES);
  for (int i = base + t; i < end; i += 256) atomicAdd(&h[dst[i] >> 7], 1);
  __syncthreads();
  for (int i = t; i < NBIN; i += 256){
    int c = h[i];
    cur[i] = c ? atomicAdd(&bincur[i], c) : 0;
  }
  __syncthreads();
  for (int i = base + t; i < end; i += 256){
    int d = dst[i], sv = src[i];
    int b = d >> 7;
    int p = atomicAdd(&cur[b], 1);
    rec[p] = (u32)(((d & 127) << 16) | sv);
  }
}

// ---- CSR step 2: per-bin node-ordered segment; rp[node] = (start<<11)|deg ---
// col aliases rec (segment fully staged in LDS before overwrite).
__global__ void k_bincsr(const u32* __restrict__ rec, const int* __restrict__ bincur,
                         u32* __restrict__ rp, int* __restrict__ col){
  __shared__ u32 recs[MAXBIN];
  __shared__ int colL[MAXBIN];
  __shared__ int deg[BINSZ];
  __shared__ int cursor[BINSZ];
  __shared__ int sc[BINSZ];
  int b = blockIdx.x, t = threadIdx.x;
  int s0 = b*MAXBIN;
  int n = bincur[b] - s0;
  if (t < BINSZ) deg[t] = 0;
  for (int i = t; i < n; i += 256) recs[i] = rec[s0 + i];
  __syncthreads();
  for (int i = t; i < n; i += 256) atomicAdd(&deg[(recs[i] >> 16) & 127], 1);
  __syncthreads();
  if (t < BINSZ) sc[t] = deg[t];
  __syncthreads();
  for (int off = 1; off < BINSZ; off <<= 1){
    int u = 0;
    if (t < BINSZ && t >= off) u = sc[t - off];
    __syncthreads();
    if (t < BINSZ) sc[t] += u;
    __syncthreads();
  }
  if (t < BINSZ){
    int d = deg[t];
    int pref = sc[t] - d;
    cursor[t] = pref;
    int node = b*BINSZ + t;
    if (node < N_NODES) rp[node] = (u32)((s0 + pref) << 11) | (u32)min(d, 2047);
  }
  __syncthreads();
  for (int i = t; i < n; i += 256){
    u32 r = recs[i];
    int p = atomicAdd(&cursor[(r >> 16) & 127], 1);
    colL[p] = (int)(r & 0xFFFFu);
  }
  __syncthreads();
  for (int i = t; i < n; i += 256) col[s0 + i] = colL[i];
}

// ---- Aggregation: M[i] = (1/deg) * sum_{j in N(i)} X[j]  (bf16 out) --------
// One wave per node; half-waves process alternate edges with uint2 (4ch) loads.
__global__ void k_aggm(const u16* __restrict__ X, const u32* __restrict__ rp,
                       const int* __restrict__ col, u16* __restrict__ M){
  int wave = threadIdx.x >> 6, lane = threadIdx.x & 63;
  int node = blockIdx.x*4 + wave;                 // grid covers exactly 50000
  u32 r = rp[node];
  int s = (int)(r >> 11), d = (int)(r & 2047);
  int e = s + d;
  int sub = lane >> 5, ln = lane & 31;
  const uint2* Xu = (const uint2*)X;
  float a0 = 0.f, a1 = 0.f, a2 = 0.f, a3 = 0.f;
  for (int cb = s; cb < e; cb += 64){
    int cnt = min(64, e - cb);
    int idx = 0;
    if (cb + lane < e) idx = col[cb + lane];
    int k = 0;
    for (; k + 4 <= cnt; k += 4){
      int jA = __shfl(idx, k + sub);
      int jB = __shfl(idx, k + 2 + sub);
      uint2 vA = Xu[jA*32 + ln];
      uint2 vB = Xu[jB*32 + ln];
      a0 += blo(vA.x); a1 += bhi(vA.x); a2 += blo(vA.y); a3 += bhi(vA.y);
      a0 += blo(vB.x); a1 += bhi(vB.x); a2 += blo(vB.y); a3 += bhi(vB.y);
    }
    for (; k + 2 <= cnt; k += 2){
      int j = __shfl(idx, k + sub);
      uint2 v = Xu[j*32 + ln];
      a0 += blo(v.x); a1 += bhi(v.x); a2 += blo(v.y); a3 += bhi(v.y);
    }
    if (k < cnt){
      int j = __shfl(idx, k);
      if (sub == 0){
        uint2 v = Xu[j*32 + ln];
        a0 += blo(v.x); a1 += bhi(v.x); a2 += blo(v.y); a3 += bhi(v.y);
      }
    }
  }
  a0 += __shfl_xor(a0, 32); a1 += __shfl_xor(a1, 32);
  a2 += __shfl_xor(a2, 32); a3 += __shfl_xor(a3, 32);
  if (sub == 0){
    float di = 1.0f / (float)max(d, 1);
    ((uint2*)M)[node*32 + ln] = make_uint2(pack2(a0*di, a1*di), pack2(a2*di, a3*di));
  }
}

// ---- GEMM: Xout = relu([M|X] @ Wcat2 + brel)  (M=50000, K=256, N=128) ------
__launch_bounds__(256, 2)
__global__ void k_gemm2(const u16* __restrict__ M, const u16* __restrict__ X,
                        const u16* __restrict__ Wcat, const float* __restrict__ brel,
                        u16* __restrict__ Xout){
  __shared__ u16 Bs[128*256];
  {
    const uint4* s = (const uint4*)Wcat;
    uint4* d = (uint4*)Bs;
    #pragma unroll
    for (int i = 0; i < 16; i++) d[threadIdx.x + 256*i] = s[threadIdx.x + 256*i];
  }
  __syncthreads();

  int wave = threadIdx.x >> 6, lane = threadIdx.x & 63;
  int l15 = lane & 15, quad = lane >> 4;
  int wy = wave >> 1, wx = wave & 1;
  int rowBase = blockIdx.x*128 + wy*64;

  floatx4 acc[4][4] = {};

  #pragma unroll
  for (int k0 = 0; k0 < 256; k0 += 32){
    const u16* Asrc = (k0 < 128) ? M : X;
    int kk = k0 & 127;
    int c = (k0 >> 3) + quad;
    short8 a[4];
    #pragma unroll
    for (int mt = 0; mt < 4; mt++){
      int row = rowBase + mt*16 + l15;
      if (row > N_NODES-1) row = N_NODES-1;   // clamp; stores are masked
      a[mt] = *(const short8*)(Asrc + row*128 + kk + quad*8);
    }
    #pragma unroll
    for (int nt = 0; nt < 4; nt++){
      int n = wx*64 + nt*16 + l15;
      short8 b = *(const short8*)(Bs + n*256 + ((c ^ (n & 15)) << 3));
      #pragma unroll
      for (int mt = 0; mt < 4; mt++)
        acc[mt][nt] = __builtin_amdgcn_mfma_f32_16x16x32_bf16(a[mt], b, acc[mt][nt], 0, 0, 0);
    }
  }

  float bc[4];
  #pragma unroll
  for (int nt = 0; nt < 4; nt++) bc[nt] = brel[wx*64 + nt*16 + l15];

  #pragma unroll
  for (int mt = 0; mt < 4; mt++){
    int rbase = rowBase + mt*16 + quad*4;
    #pragma unroll
    for (int r = 0; r < 4; r++){
      int row = rbase + r;
      if (row < N_NODES){
        #pragma unroll
        for (int nt = 0; nt < 4; nt++){
          int n = wx*64 + nt*16 + l15;
          Xout[row*128 + n] = f2b(fmaxf(acc[mt][nt][r] + bc[nt], 0.f));
        }
      }
    }
  }
}

// ---- fused pool + conv3 (f32 math): Gb[g] = pool(M3)@Wrel3 + pool(X3)@Wroot3 + brel3
__launch_bounds__(256)
__global__ void k_poolconv(const u16* __restrict__ M3, const u16* __restrict__ X3,
                           const int* __restrict__ start,
                           const float* __restrict__ Wrel, const float* __restrict__ Wroot,
                           const float* __restrict__ brel, u16* __restrict__ Gb){
  __shared__ float2 pm[4][64], px[4][64];
  __shared__ float pmS[128], pxS[128], part[256];
  int gid = blockIdx.x;
  int wave = threadIdx.x >> 6, lane = threadIdx.x & 63;
  int s = start[gid], e = start[gid+1];
  const u32* Mu = (const u32*)M3;
  const u32* Xu = (const u32*)X3;
  float m0 = 0.f, m1 = 0.f, x0 = 0.f, x1 = 0.f;
  for (int i = s + wave; i < e; i += 4){
    u32 vm = Mu[i*64 + lane];
    u32 vx = Xu[i*64 + lane];
    m0 += blo(vm); m1 += bhi(vm);
    x0 += blo(vx); x1 += bhi(vx);
  }
  pm[wave][lane] = make_float2(m0, m1);
  px[wave][lane] = make_float2(x0, x1);
  __syncthreads();
  if (wave == 0){
    float inv = 1.0f / (float)max(e - s, 1);
    float2 a0 = pm[0][lane], a1 = pm[1][lane], a2 = pm[2][lane], a3 = pm[3][lane];
    float2 b0 = px[0][lane], b1 = px[1][lane], b2 = px[2][lane], b3 = px[3][lane];
    pmS[2*lane]   = ((a0.x+a1.x)+(a2.x+a3.x))*inv;
    pmS[2*lane+1] = ((a0.y+a1.y)+(a2.y+a3.y))*inv;
    pxS[2*lane]   = ((b0.x+b1.x)+(b2.x+b3.x))*inv;
    pxS[2*lane+1] = ((b0.y+b1.y)+(b2.y+b3.y))*inv;
  }
  __syncthreads();
  int t = threadIdx.x;
  int n = t & 127, half = t >> 7;
  const float* W = half ? Wroot : Wrel;
  const float* S = half ? pxS : pmS;
  float a = 0.f;
  for (int k = 0; k < 128; k++) a = fmaf(S[k], W[k*128 + n], a);
  part[t] = a;
  __syncthreads();
  if (t < 128) Gb[gid*128 + t] = f2b(part[t] + part[t + 128] + brel[t]);
}

// ---- fused MLP: Gb[512,128] @W1 relu @W2 relu @Wo + biases ------------------
#define APAD 136
__launch_bounds__(256)
__global__ void k_mlp(const u16* __restrict__ Gb, const u16* __restrict__ wm,
                      const float* __restrict__ b1, const float* __restrict__ b2,
                      const float* __restrict__ Wo, const float* __restrict__ bo,
                      float* __restrict__ out){
  __shared__ u16 Apad[128*APAD];
  int t = threadIdx.x;
  int wave = t >> 6, lane = t & 63;
  int l15 = lane & 15, quad = lane >> 4;
  int R = blockIdx.x*128;

  floatx4 acc[2][8] = {};
  #pragma unroll
  for (int k0 = 0; k0 < 128; k0 += 32){
    short8 a[2];
    #pragma unroll
    for (int mt = 0; mt < 2; mt++){
      int row = R + (wave*2 + mt)*16 + l15;
      a[mt] = *(const short8*)(Gb + row*128 + k0 + quad*8);
    }
    #pragma unroll
    for (int nt = 0; nt < 8; nt++){
      int n = nt*16 + l15;
      short8 b = *(const short8*)(wm + n*128 + k0 + quad*8);
      #pragma unroll
      for (int mt = 0; mt < 2; mt++)
        acc[mt][nt] = __builtin_amdgcn_mfma_f32_16x16x32_bf16(a[mt], b, acc[mt][nt], 0, 0, 0);
    }
  }
  #pragma unroll
  for (int nt = 0; nt < 8; nt++){
    int coln = nt*16 + l15;
    float bc = b1[coln];
    #pragma unroll
    for (int mt = 0; mt < 2; mt++){
      int lmb = (wave*2 + mt)*16 + quad*4;
      #pragma unroll
      for (int r = 0; r < 4; r++)
        Apad[(lmb + r)*APAD + coln] = f2b(fmaxf(acc[mt][nt][r] + bc, 0.f));
    }
  }
  __syncthreads();

  floatx4 acc2[2][8] = {};
  #pragma unroll
  for (int k0 = 0; k0 < 128; k0 += 32){
    short8 a[2];
    #pragma unroll
    for (int mt = 0; mt < 2; mt++){
      int lm = (wave*2 + mt)*16 + l15;
      a[mt] = *(const short8*)(Apad + lm*APAD + k0 + quad*8);
    }
    #pragma unroll
    for (int nt = 0; nt < 8; nt++){
      int n = nt*16 + l15;
      short8 b = *(const short8*)(wm + 16384 + n*128 + k0 + quad*8);
      #pragma unroll
      for (int mt = 0; mt < 2; mt++)
        acc2[mt][nt] = __builtin_amdgcn_mfma_f32_16x16x32_bf16(a[mt], b, acc2[mt][nt], 0, 0, 0);
    }
  }
  __syncthreads();
  #pragma unroll
  for (int nt = 0; nt < 8; nt++){
    int coln = nt*16 + l15;
    float bc = b2[coln];
    #pragma unroll
    for (int mt = 0; mt < 2; mt++){
      int lmb = (wave*2 + mt)*16 + quad*4;
      #pragma unroll
      for (int r = 0; r < 4; r++)
        Apad[(lmb + r)*APAD + coln] = f2b(fmaxf(acc2[mt][nt][r] + bc, 0.f));
    }
  }
  __syncthreads();

  int row = t >> 1;
  int c0  = (t & 1)*4;
  float o0 = bo[c0], o1 = bo[c0+1], o2 = bo[c0+2], o3 = bo[c0+3];
  for (int k = 0; k < 128; k++){
    float h = b2f(Apad[row*APAD + k]);
    const float* w = Wo + k*8 + c0;
    o0 = fmaf(h, w[0], o0); o1 = fmaf(h, w[1], o1);
    o2 = fmaf(h, w[2], o2); o3 = fmaf(h, w[3], o3);
  }
  float* op = out + (R + row)*8 + c0;
  op[0] = o0; op[1] = o1; op[2] = o2; op[3] = o3;
}

extern "C" void kernel_launch(void* const* d_in, const int* in_sizes, int n_in,
                              void* d_out, int out_size, void* d_ws, size_t ws_size,
                              hipStream_t stream){
  const float* x     = (const float*)d_in[0];
  const int*   ei    = (const int*)d_in[1];
  const int*   batch = (const int*)d_in[2];
  const float* Wrel1 = (const float*)d_in[3];
  const float* brel1 = (const float*)d_in[4];
  const float* Wroot1= (const float*)d_in[5];
  const float* Wrel2 = (const float*)d_in[6];
  const float* brel2 = (const float*)d_in[7];
  const float* Wroot2= (const float*)d_in[8];
  const float* Wrel3 = (const float*)d_in[9];
  const float* brel3 = (const float*)d_in[10];
  const float* Wroot3= (const float*)d_in[11];
  const float* W1 = (const float*)d_in[12]; const float* b1 = (const float*)d_in[13];
  const float* W2 = (const float*)d_in[14]; const float* b2 = (const float*)d_in[15];
  const float* Wo = (const float*)d_in[16]; const float* bo = (const float*)d_in[17];
  const int* esrc = ei;
  const int* edst = ei + N_EDGES;

  char* ws = (char*)d_ws;
  size_t off = 0;
  auto alloc = [&](size_t bytes)->char*{
    char* p = ws + off; off += (bytes + 255) & ~(size_t)255; return p;
  };
  u16*   X1     = (u16*)  alloc((size_t)N_NODES*128*2);
  u16*   X2     = (u16*)  alloc((size_t)N_NODES*128*2);
  u16*   X3     = (u16*)  alloc((size_t)N_NODES*128*2);
  u16*   Mb     = (u16*)  alloc((size_t)N_NODES*128*2);
  u16*   wcat   = (u16*)  alloc((size_t)2*128*256*2);
  u16*   wm     = (u16*)  alloc((size_t)2*128*128*2);
  u16*   Gb     = (u16*)  alloc((size_t)N_GRAPHS*128*2);
  u32*   rp     = (u32*)  alloc((size_t)N_NODES*4);
  int*   colIdx = (int*)  alloc((size_t)NBIN*MAXBIN*4);   // doubles as rec buffer
  int*   start  = (int*)  alloc((size_t)(N_GRAPHS+1)*4);
  int*   bincur = (int*)  alloc((size_t)NBIN*4);
  u32*   rec    = (u32*)colIdx;

  dim3 b256(256);
  k_prep    <<<PREP_CUR, b256, 0, stream>>>((const float4*)x, (uint2*)X1,
                                            Wrel1, Wroot1, Wrel2, Wroot2, wcat,
                                            W1, W2, wm, batch, start, bincur);
  k_scatter2<<<NCHUNK, b256, 0, stream>>>(esrc, edst, bincur, rec);
  k_bincsr  <<<NBIN, b256, 0, stream>>>(rec, bincur, rp, colIdx);

  const int ggrid = (N_NODES + 127)/128;   // 391
  const int agrid = N_NODES/4;             // 12500

  k_aggm <<<agrid, b256, 0, stream>>>(X1, rp, colIdx, Mb);
  k_gemm2<<<ggrid, b256, 0, stream>>>(Mb, X1, wcat + 0*32768, brel1, X2);

  k_aggm <<<agrid, b256, 0, stream>>>(X2, rp, colIdx, Mb);
  k_gemm2<<<ggrid, b256, 0, stream>>>(Mb, X2, wcat + 1*32768, brel2, X3);

  k_aggm <<<agrid, b256, 0, stream>>>(X3, rp, colIdx, Mb);

  k_poolconv<<<N_GRAPHS, b256, 0, stream>>>(Mb, X3, start, Wrel3, Wroot3, brel3, Gb);
  k_mlp     <<<4, b256, 0, stream>>>(Gb, wm, b1, b2, Wo, bo, (float*)d_out);
}